// Round 3
// baseline (5363.010 us; speedup 1.0000x reference)
//
#include <hip/hip_runtime.h>
#include <math.h>

// Problem constants (from reference)
#define DMODEL 1024
#define NHEAD  16
#define HD     64
#define DFF    4096
#define SEQ    2048
#define BATCH  2
#define NTOK   (BATCH * SEQ)   // 4096
#define LN_EPS 1e-5f

// ---------------------------------------------------------------------------
// LayerNorm: one block per row (D=1024), 256 threads x float4
// ---------------------------------------------------------------------------
__global__ __launch_bounds__(256) void ln_kernel(
    const float* __restrict__ x, const float* __restrict__ g,
    const float* __restrict__ beta, float* __restrict__ out) {
  int row = blockIdx.x;
  const float4* xr = (const float4*)(x + (size_t)row * DMODEL);
  float4 v = xr[threadIdx.x];
  float s  = v.x + v.y + v.z + v.w;
  float sq = v.x * v.x + v.y * v.y + v.z * v.z + v.w * v.w;
#pragma unroll
  for (int off = 1; off < 64; off <<= 1) {
    s  += __shfl_xor(s, off);
    sq += __shfl_xor(sq, off);
  }
  __shared__ float red_s[4], red_q[4];
  int wave = threadIdx.x >> 6, lane = threadIdx.x & 63;
  if (lane == 0) { red_s[wave] = s; red_q[wave] = sq; }
  __syncthreads();
  s  = red_s[0] + red_s[1] + red_s[2] + red_s[3];
  sq = red_q[0] + red_q[1] + red_q[2] + red_q[3];
  float mu  = s * (1.0f / DMODEL);
  float var = sq * (1.0f / DMODEL) - mu * mu;
  float r   = rsqrtf(var + LN_EPS);
  float4 gv = ((const float4*)g)[threadIdx.x];
  float4 bv = ((const float4*)beta)[threadIdx.x];
  float4 o;
  o.x = (v.x - mu) * r * gv.x + bv.x;
  o.y = (v.y - mu) * r * gv.y + bv.y;
  o.z = (v.z - mu) * r * gv.z + bv.z;
  o.w = (v.w - mu) * r * gv.w + bv.w;
  ((float4*)(out + (size_t)row * DMODEL))[threadIdx.x] = o;
}

// ---------------------------------------------------------------------------
// Repack Wq/Wk/Wv (H,D,HD) into one row-major (D x 3072) matrix:
//   col = m*1024 + h*64 + k   (m: 0=q,1=k,2=v)
// ---------------------------------------------------------------------------
__global__ __launch_bounds__(256) void repack_qkv(
    const float* __restrict__ Wq, const float* __restrict__ Wk,
    const float* __restrict__ Wv, float* __restrict__ Wc) {
  int idx = blockIdx.x * 256 + threadIdx.x;  // over D*3072
  int col = idx % 3072;
  int d   = idx / 3072;
  int m   = col >> 10;
  int c   = col & 1023;
  const float* W = (m == 0) ? Wq : (m == 1 ? Wk : Wv);
  int hh = c >> 6, kk = c & 63;
  Wc[idx] = W[((size_t)hh * DMODEL + d) * HD + kk];
}

// ---------------------------------------------------------------------------
// fp32 GEMM: C[M x N] = A[M x K] @ B[K x N], row-major, tiles 128x128, BK=8.
// 256 threads, 8x8 micro-tile per thread. LDS double-buffered: ONE
// __syncthreads per K-step; global loads for tile k+1 issue before compute
// on tile k so HBM latency hides under the 512-FMA inner loop.
// Optional epilogue: +bias[col], +res[row,col], ReLU.
// M,N multiples of 128; K multiple of 8 (all true here).
// ---------------------------------------------------------------------------
template <int BIAS, int RES, int RELU>
__global__ __launch_bounds__(256) void gemm_k(
    const float* __restrict__ A, const float* __restrict__ Bm,
    const float* __restrict__ bias, const float* __restrict__ res,
    float* __restrict__ C, int M, int N, int K) {
  __shared__ float As[2][8][128];  // transposed A tile: As[buf][k][m]
  __shared__ float Bs[2][8][128];
  int tid = threadIdx.x;
  int m0 = blockIdx.y * 128, n0 = blockIdx.x * 128;
  int tx = tid & 15, ty = tid >> 4;

  int arow = tid >> 1, acol = (tid & 1) * 4;   // A tile load: 128 rows x 8 cols
  int brow = tid >> 5, bcol = (tid & 31) * 4;  // B tile load: 8 rows x 128 cols
  const float* Aptr = A + (size_t)(m0 + arow) * K + acol;
  const float* Bptr = Bm + (size_t)brow * N + n0 + bcol;

  float acc[8][8];
#pragma unroll
  for (int i = 0; i < 8; i++)
#pragma unroll
    for (int j = 0; j < 8; j++) acc[i][j] = 0.f;

  // prologue: stage tile 0 into buffer 0
  {
    float4 av = *(const float4*)Aptr;
    float4 bv = *(const float4*)Bptr;
    As[0][acol + 0][arow] = av.x;
    As[0][acol + 1][arow] = av.y;
    As[0][acol + 2][arow] = av.z;
    As[0][acol + 3][arow] = av.w;
    *(float4*)&Bs[0][brow][bcol] = bv;
  }
  __syncthreads();

  for (int k0 = 0; k0 < K; k0 += 8) {
    int cur = (k0 >> 3) & 1;
    bool more = (k0 + 8) < K;
    float4 av, bv;
    if (more) {
      av = *(const float4*)(Aptr + 8);
      bv = *(const float4*)(Bptr + (size_t)8 * N);
      Aptr += 8;
      Bptr += (size_t)8 * N;
    }
#pragma unroll
    for (int kk = 0; kk < 8; kk++) {
      float a[8], b[8];
      *(float4*)&a[0] = *(const float4*)&As[cur][kk][ty * 4];
      *(float4*)&a[4] = *(const float4*)&As[cur][kk][64 + ty * 4];
      *(float4*)&b[0] = *(const float4*)&Bs[cur][kk][tx * 4];
      *(float4*)&b[4] = *(const float4*)&Bs[cur][kk][64 + tx * 4];
#pragma unroll
      for (int i = 0; i < 8; i++)
#pragma unroll
        for (int j = 0; j < 8; j++) acc[i][j] += a[i] * b[j];
    }
    if (more) {
      // Safe without a pre-barrier: the barrier at the END of iteration i-1
      // guaranteed all waves finished reading buffer cur^1.
      int nxt = cur ^ 1;
      As[nxt][acol + 0][arow] = av.x;
      As[nxt][acol + 1][arow] = av.y;
      As[nxt][acol + 2][arow] = av.z;
      As[nxt][acol + 3][arow] = av.w;
      *(float4*)&Bs[nxt][brow][bcol] = bv;
      __syncthreads();
    }
  }

#pragma unroll
  for (int i = 0; i < 8; i++) {
    int r = m0 + ((i < 4) ? (ty * 4 + i) : (64 + ty * 4 + i - 4));
#pragma unroll
    for (int jh = 0; jh < 2; jh++) {
      int c = n0 + ((jh == 0) ? (tx * 4) : (64 + tx * 4));
      float4 o;
      o.x = acc[i][jh * 4 + 0];
      o.y = acc[i][jh * 4 + 1];
      o.z = acc[i][jh * 4 + 2];
      o.w = acc[i][jh * 4 + 3];
      if (BIAS) {
        float4 bv = *(const float4*)&bias[c];
        o.x += bv.x; o.y += bv.y; o.z += bv.z; o.w += bv.w;
      }
      if (RES) {
        float4 rv = *(const float4*)&res[(size_t)r * N + c];
        o.x += rv.x; o.y += rv.y; o.z += rv.z; o.w += rv.w;
      }
      if (RELU) {
        o.x = fmaxf(o.x, 0.f); o.y = fmaxf(o.y, 0.f);
        o.z = fmaxf(o.z, 0.f); o.w = fmaxf(o.w, 0.f);
      }
      *(float4*)&C[(size_t)r * N + c] = o;
    }
  }
}

// ---------------------------------------------------------------------------
// Causal flash attention, fp32, 2 query rows per thread (interleaved).
// qkv layout: row t = b*SEQ+s, 3072 cols: q at h*64, k at 1024+h*64,
// v at 2048+h*64. Grid: (SEQ/128, NHEAD, BATCH), 64 threads (1 wave).
// Thread handles rows s0 = qb*128 + 2*tid and s1 = s0+1, so each broadcast
// K/V LDS read feeds 8 FMAs (halves LDS-port instruction count vs 1-row).
// Output: out[t*1024 + h*64 + d]  (concat-heads layout of the reference).
// ---------------------------------------------------------------------------
#define KT 16
__global__ __launch_bounds__(64) void attn_kernel(
    const float* __restrict__ qkv, float* __restrict__ out) {
  int qb = blockIdx.x, h = blockIdx.y, b = blockIdx.z;
  int tid = threadIdx.x;
  int s0 = qb * 128 + 2 * tid;
  int s1 = s0 + 1;

  __shared__ float K_lds[KT][HD];
  __shared__ float V_lds[KT][HD];

  float q0[HD], q1[HD], o0[HD], o1[HD];
  {
    const float4* qp0 = (const float4*)(qkv + (size_t)(b * SEQ + s0) * 3072 + h * HD);
    const float4* qp1 = (const float4*)(qkv + (size_t)(b * SEQ + s1) * 3072 + h * HD);
#pragma unroll
    for (int i = 0; i < 16; i++) {
      float4 t0 = qp0[i];
      float4 t1 = qp1[i];
      q0[4 * i + 0] = t0.x * 0.125f;  // * HD^-0.5
      q0[4 * i + 1] = t0.y * 0.125f;
      q0[4 * i + 2] = t0.z * 0.125f;
      q0[4 * i + 3] = t0.w * 0.125f;
      q1[4 * i + 0] = t1.x * 0.125f;
      q1[4 * i + 1] = t1.y * 0.125f;
      q1[4 * i + 2] = t1.z * 0.125f;
      q1[4 * i + 3] = t1.w * 0.125f;
    }
  }
#pragma unroll
  for (int d = 0; d < HD; d++) { o0[d] = 0.f; o1[d] = 0.f; }
  float m0 = -1e30f, l0 = 0.f, m1 = -1e30f, l1 = 0.f;

  int ntiles = qb * 8 + 8;  // keys 0 .. qb*128+127 (diagonal block included)
  for (int t = 0; t < ntiles; t++) {
    int k0 = t * KT;
    __syncthreads();
    {
      const float* kbase = qkv + (size_t)(b * SEQ + k0) * 3072 + 1024 + h * HD;
      const float* vbase = kbase + 1024;
#pragma unroll
      for (int i = 0; i < 4; i++) {
        int f = tid + 64 * i;            // 0..255 float4 slots (16 rows x 16)
        int row = f >> 4, c4 = (f & 15) * 4;
        *(float4*)&K_lds[row][c4] = *(const float4*)(kbase + (size_t)row * 3072 + c4);
        *(float4*)&V_lds[row][c4] = *(const float4*)(vbase + (size_t)row * 3072 + c4);
      }
    }
    __syncthreads();

    float p0[KT], p1[KT];
    float tmax0 = -1e30f, tmax1 = -1e30f;
#pragma unroll
    for (int j = 0; j < KT; j++) {
      float sc0 = 0.f, sc1 = 0.f;
#pragma unroll
      for (int d4 = 0; d4 < 16; d4++) {
        float4 kv = *(const float4*)&K_lds[j][d4 * 4];
        sc0 += q0[d4 * 4 + 0] * kv.x + q0[d4 * 4 + 1] * kv.y +
               q0[d4 * 4 + 2] * kv.z + q0[d4 * 4 + 3] * kv.w;
        sc1 += q1[d4 * 4 + 0] * kv.x + q1[d4 * 4 + 1] * kv.y +
               q1[d4 * 4 + 2] * kv.z + q1[d4 * 4 + 3] * kv.w;
      }
      if (k0 + j > s0) sc0 = -1e30f;  // causal mask
      if (k0 + j > s1) sc1 = -1e30f;
      p0[j] = sc0;
      p1[j] = sc1;
      tmax0 = fmaxf(tmax0, sc0);
      tmax1 = fmaxf(tmax1, sc1);
    }
    float mn0 = fmaxf(m0, tmax0);
    float mn1 = fmaxf(m1, tmax1);
    float sc0 = __expf(m0 - mn0);
    float sc1 = __expf(m1 - mn1);
    l0 *= sc0;
    l1 *= sc1;
#pragma unroll
    for (int d = 0; d < HD; d++) { o0[d] *= sc0; o1[d] *= sc1; }
#pragma unroll
    for (int j = 0; j < KT; j++) {
      float pj0 = __expf(p0[j] - mn0);
      float pj1 = __expf(p1[j] - mn1);
      l0 += pj0;
      l1 += pj1;
#pragma unroll
      for (int d4 = 0; d4 < 16; d4++) {
        float4 vv = *(const float4*)&V_lds[j][d4 * 4];
        o0[d4 * 4 + 0] += pj0 * vv.x;
        o0[d4 * 4 + 1] += pj0 * vv.y;
        o0[d4 * 4 + 2] += pj0 * vv.z;
        o0[d4 * 4 + 3] += pj0 * vv.w;
        o1[d4 * 4 + 0] += pj1 * vv.x;
        o1[d4 * 4 + 1] += pj1 * vv.y;
        o1[d4 * 4 + 2] += pj1 * vv.z;
        o1[d4 * 4 + 3] += pj1 * vv.w;
      }
    }
    m0 = mn0;
    m1 = mn1;
  }

  float inv0 = 1.f / l0;
  float inv1 = 1.f / l1;
  float* op0 = out + (size_t)(b * SEQ + s0) * DMODEL + h * HD;
  float* op1 = out + (size_t)(b * SEQ + s1) * DMODEL + h * HD;
#pragma unroll
  for (int d4 = 0; d4 < 16; d4++) {
    float4 t0, t1;
    t0.x = o0[d4 * 4 + 0] * inv0;
    t0.y = o0[d4 * 4 + 1] * inv0;
    t0.z = o0[d4 * 4 + 2] * inv0;
    t0.w = o0[d4 * 4 + 3] * inv0;
    t1.x = o1[d4 * 4 + 0] * inv1;
    t1.y = o1[d4 * 4 + 1] * inv1;
    t1.z = o1[d4 * 4 + 2] * inv1;
    t1.w = o1[d4 * 4 + 3] * inv1;
    *(float4*)(op0 + d4 * 4) = t0;
    *(float4*)(op1 + d4 * 4) = t1;
  }
}

// ---------------------------------------------------------------------------
// Orchestration
// ---------------------------------------------------------------------------
extern "C" void kernel_launch(void* const* d_in, const int* in_sizes, int n_in,
                              void* d_out, int out_size, void* d_ws, size_t ws_size,
                              hipStream_t stream) {
  const float* x     = (const float*)d_in[0];
  const float* Wq    = (const float*)d_in[1];
  const float* Wk    = (const float*)d_in[2];
  const float* Wv    = (const float*)d_in[3];
  const float* Wp    = (const float*)d_in[4];
  const float* bp    = (const float*)d_in[5];
  const float* W1    = (const float*)d_in[6];
  const float* b1    = (const float*)d_in[7];
  const float* W2    = (const float*)d_in[8];
  const float* b2    = (const float*)d_in[9];
  const float* g1    = (const float*)d_in[10];
  const float* beta1 = (const float*)d_in[11];
  const float* g2    = (const float*)d_in[12];
  const float* beta2 = (const float*)d_in[13];
  float* out = (float*)d_out;

  // Workspace layout (floats). Total 28,311,552 floats = ~108 MB.
  float* wsf = (float*)d_ws;
  float* h   = wsf;                                   // NTOK*DMODEL  (LN out; reused as attn_out, then LN2 out)
  float* Wc  = h + (size_t)NTOK * DMODEL;             // DMODEL*3072  (packed QKV weights)
  float* big = Wc + (size_t)DMODEL * 3072;            // max(NTOK*3072, NTOK*DFF) = NTOK*DFF (qkv, then ffn act)
  float* x1  = big + (size_t)NTOK * DFF;              // NTOK*DMODEL  (post-attention residual)
  float* qkv = big;
  float* ffn = big;
  float* attno = h;  // reuse: h (LN1 out) is dead after the QKV GEMM

  // 1. LN1
  ln_kernel<<<NTOK, 256, 0, stream>>>(x, g1, beta1, h);
  // 2. pack QKV weights
  repack_qkv<<<(DMODEL * 3072) / 256, 256, 0, stream>>>(Wq, Wk, Wv, Wc);
  // 3. QKV = h @ Wc   (4096 x 3072, K=1024)
  gemm_k<0, 0, 0><<<dim3(3072 / 128, NTOK / 128), 256, 0, stream>>>(
      h, Wc, nullptr, nullptr, qkv, NTOK, 3072, DMODEL);
  // 4. causal attention -> attno (concat-head layout)
  attn_kernel<<<dim3(SEQ / 128, NHEAD, BATCH), 64, 0, stream>>>(qkv, attno);
  // 5. x1 = x + attno @ Wp + bp
  gemm_k<1, 1, 0><<<dim3(DMODEL / 128, NTOK / 128), 256, 0, stream>>>(
      attno, Wp, bp, x, x1, NTOK, DMODEL, DMODEL);
  // 6. LN2 (h buffer free again)
  ln_kernel<<<NTOK, 256, 0, stream>>>(x1, g2, beta2, h);
  // 7. ffn = relu(h @ W1 + b1)   (4096 x 4096, K=1024) — overlays dead qkv
  gemm_k<1, 0, 1><<<dim3(DFF / 128, NTOK / 128), 256, 0, stream>>>(
      h, W1, b1, nullptr, ffn, NTOK, DFF, DMODEL);
  // 8. out = x1 + ffn @ W2 + b2  (4096 x 1024, K=4096)
  gemm_k<1, 1, 0><<<dim3(DMODEL / 128, NTOK / 128), 256, 0, stream>>>(
      ffn, W2, b2, x1, out, NTOK, DMODEL, DFF);
}

// Round 6
// 2614.857 us; speedup vs baseline: 2.0510x; 2.0510x over previous
//
#include <hip/hip_runtime.h>
#include <math.h>

// Problem constants (from reference)
#define DMODEL 1024
#define NHEAD  16
#define HD     64
#define DFF    4096
#define SEQ    2048
#define BATCH  2
#define NTOK   (BATCH * SEQ)   // 4096
#define LN_EPS 1e-5f

// ---------------------------------------------------------------------------
// LayerNorm: one block per row (D=1024), 256 threads x float4
// ---------------------------------------------------------------------------
__global__ __launch_bounds__(256) void ln_kernel(
    const float* __restrict__ x, const float* __restrict__ g,
    const float* __restrict__ beta, float* __restrict__ out) {
  int row = blockIdx.x;
  const float4* xr = (const float4*)(x + (size_t)row * DMODEL);
  float4 v = xr[threadIdx.x];
  float s  = v.x + v.y + v.z + v.w;
  float sq = v.x * v.x + v.y * v.y + v.z * v.z + v.w * v.w;
#pragma unroll
  for (int off = 1; off < 64; off <<= 1) {
    s  += __shfl_xor(s, off);
    sq += __shfl_xor(sq, off);
  }
  __shared__ float red_s[4], red_q[4];
  int wave = threadIdx.x >> 6, lane = threadIdx.x & 63;
  if (lane == 0) { red_s[wave] = s; red_q[wave] = sq; }
  __syncthreads();
  s  = red_s[0] + red_s[1] + red_s[2] + red_s[3];
  sq = red_q[0] + red_q[1] + red_q[2] + red_q[3];
  float mu  = s * (1.0f / DMODEL);
  float var = sq * (1.0f / DMODEL) - mu * mu;
  float r   = rsqrtf(var + LN_EPS);
  float4 gv = ((const float4*)g)[threadIdx.x];
  float4 bv = ((const float4*)beta)[threadIdx.x];
  float4 o;
  o.x = (v.x - mu) * r * gv.x + bv.x;
  o.y = (v.y - mu) * r * gv.y + bv.y;
  o.z = (v.z - mu) * r * gv.z + bv.z;
  o.w = (v.w - mu) * r * gv.w + bv.w;
  ((float4*)(out + (size_t)row * DMODEL))[threadIdx.x] = o;
}

// ---------------------------------------------------------------------------
// Repack Wq/Wk/Wv (H,D,HD) into one row-major (D x 3072) matrix:
//   col = m*1024 + h*64 + k   (m: 0=q,1=k,2=v)
// ---------------------------------------------------------------------------
__global__ __launch_bounds__(256) void repack_qkv(
    const float* __restrict__ Wq, const float* __restrict__ Wk,
    const float* __restrict__ Wv, float* __restrict__ Wc) {
  int idx = blockIdx.x * 256 + threadIdx.x;  // over D*3072
  int col = idx % 3072;
  int d   = idx / 3072;
  int m   = col >> 10;
  int c   = col & 1023;
  const float* W = (m == 0) ? Wq : (m == 1 ? Wk : Wv);
  int hh = c >> 6, kk = c & 63;
  Wc[idx] = W[((size_t)hh * DMODEL + d) * HD + kk];
}

// ---------------------------------------------------------------------------
// fp32 GEMM: C[M x N] = A[M x K] @ B[K x N], row-major, tiles 128x128, BK=8.
// 256 threads, 8x8 micro-tile per thread. LDS double-buffered: ONE
// __syncthreads per K-step. (Unchanged from the measured round-3 baseline.)
// ---------------------------------------------------------------------------
template <int BIAS, int RES, int RELU>
__global__ __launch_bounds__(256) void gemm_k(
    const float* __restrict__ A, const float* __restrict__ Bm,
    const float* __restrict__ bias, const float* __restrict__ res,
    float* __restrict__ C, int M, int N, int K) {
  __shared__ float As[2][8][128];  // transposed A tile: As[buf][k][m]
  __shared__ float Bs[2][8][128];
  int tid = threadIdx.x;
  int m0 = blockIdx.y * 128, n0 = blockIdx.x * 128;
  int tx = tid & 15, ty = tid >> 4;

  int arow = tid >> 1, acol = (tid & 1) * 4;   // A tile load: 128 rows x 8 cols
  int brow = tid >> 5, bcol = (tid & 31) * 4;  // B tile load: 8 rows x 128 cols
  const float* Aptr = A + (size_t)(m0 + arow) * K + acol;
  const float* Bptr = Bm + (size_t)brow * N + n0 + bcol;

  float acc[8][8];
#pragma unroll
  for (int i = 0; i < 8; i++)
#pragma unroll
    for (int j = 0; j < 8; j++) acc[i][j] = 0.f;

  // prologue: stage tile 0 into buffer 0
  {
    float4 av = *(const float4*)Aptr;
    float4 bv = *(const float4*)Bptr;
    As[0][acol + 0][arow] = av.x;
    As[0][acol + 1][arow] = av.y;
    As[0][acol + 2][arow] = av.z;
    As[0][acol + 3][arow] = av.w;
    *(float4*)&Bs[0][brow][bcol] = bv;
  }
  __syncthreads();

  for (int k0 = 0; k0 < K; k0 += 8) {
    int cur = (k0 >> 3) & 1;
    bool more = (k0 + 8) < K;
    float4 av, bv;
    if (more) {
      av = *(const float4*)(Aptr + 8);
      bv = *(const float4*)(Bptr + (size_t)8 * N);
      Aptr += 8;
      Bptr += (size_t)8 * N;
    }
#pragma unroll
    for (int kk = 0; kk < 8; kk++) {
      float a[8], b[8];
      *(float4*)&a[0] = *(const float4*)&As[cur][kk][ty * 4];
      *(float4*)&a[4] = *(const float4*)&As[cur][kk][64 + ty * 4];
      *(float4*)&b[0] = *(const float4*)&Bs[cur][kk][tx * 4];
      *(float4*)&b[4] = *(const float4*)&Bs[cur][kk][64 + tx * 4];
#pragma unroll
      for (int i = 0; i < 8; i++)
#pragma unroll
        for (int j = 0; j < 8; j++) acc[i][j] += a[i] * b[j];
    }
    if (more) {
      int nxt = cur ^ 1;
      As[nxt][acol + 0][arow] = av.x;
      As[nxt][acol + 1][arow] = av.y;
      As[nxt][acol + 2][arow] = av.z;
      As[nxt][acol + 3][arow] = av.w;
      *(float4*)&Bs[nxt][brow][bcol] = bv;
      __syncthreads();
    }
  }

#pragma unroll
  for (int i = 0; i < 8; i++) {
    int r = m0 + ((i < 4) ? (ty * 4 + i) : (64 + ty * 4 + i - 4));
#pragma unroll
    for (int jh = 0; jh < 2; jh++) {
      int c = n0 + ((jh == 0) ? (tx * 4) : (64 + tx * 4));
      float4 o;
      o.x = acc[i][jh * 4 + 0];
      o.y = acc[i][jh * 4 + 1];
      o.z = acc[i][jh * 4 + 2];
      o.w = acc[i][jh * 4 + 3];
      if (BIAS) {
        float4 bv = *(const float4*)&bias[c];
        o.x += bv.x; o.y += bv.y; o.z += bv.z; o.w += bv.w;
      }
      if (RES) {
        float4 rv = *(const float4*)&res[(size_t)r * N + c];
        o.x += rv.x; o.y += rv.y; o.z += rv.z; o.w += rv.w;
      }
      if (RELU) {
        o.x = fmaxf(o.x, 0.f); o.y = fmaxf(o.y, 0.f);
        o.z = fmaxf(o.z, 0.f); o.w = fmaxf(o.w, 0.f);
      }
      *(float4*)&C[(size_t)r * N + c] = o;
    }
  }
}

// ---------------------------------------------------------------------------
// Causal flash attention, fp32. 1 q-row/thread (no spill: ~165 VGPR),
// 4 key-striped waves per block over the SAME 64 q-rows.
// Wave w processes key-tiles t ≡ w (mod 4) into its PRIVATE LDS tile —
// no __syncthreads in the K-loop (per-wave lgkmcnt ordering suffices).
// Partial (m, l, o) merged across the 4 waves via LDS at the end.
// Masked scores use -3e38 (< m-init -1e30) so fully-masked stripes
// contribute exp(-huge)=0 through the merge.
// Grid: (SEQ/64, NHEAD, BATCH) x 256 threads.
// ---------------------------------------------------------------------------
#define KT 16
#define NSTRIPE 4
__global__ __launch_bounds__(256) void attn_kernel(
    const float* __restrict__ qkv, float* __restrict__ out) {
  int qb = blockIdx.x, h = blockIdx.y, b = blockIdx.z;
  int tid = threadIdx.x;
  int wv = tid >> 6, lane = tid & 63;
  int s = qb * 64 + lane;  // this thread's query row

  __shared__ float smem[NSTRIPE][2][KT][HD];  // per-wave K/V tiles, 32 KB

  float q[HD], o[HD];
  {
    const float4* qp = (const float4*)(qkv + (size_t)(b * SEQ + s) * 3072 + h * HD);
#pragma unroll
    for (int i = 0; i < 16; i++) {
      float4 t = qp[i];
      q[4 * i + 0] = t.x * 0.125f;  // * HD^-0.5
      q[4 * i + 1] = t.y * 0.125f;
      q[4 * i + 2] = t.z * 0.125f;
      q[4 * i + 3] = t.w * 0.125f;
    }
  }
#pragma unroll
  for (int d = 0; d < HD; d++) o[d] = 0.f;
  float m = -1e30f, l = 0.f;

  int ntiles = 4 * qb + 4;  // key tiles covering keys 0 .. qb*64+63
  const float* kbase0 = qkv + (size_t)(b * SEQ) * 3072 + 1024 + h * HD;

  for (int t = wv; t < ntiles; t += NSTRIPE) {
    int k0 = t * KT;
    const float* kbase = kbase0 + (size_t)k0 * 3072;
    // stage this wave's 16x64 K and V tiles (4+4 float4 per lane)
#pragma unroll
    for (int i = 0; i < 4; i++) {
      int f = lane + 64 * i;  // 0..255 float4 slots
      int row = f >> 4, c4 = (f & 15) * 4;
      const float* src = kbase + (size_t)row * 3072 + c4;
      *(float4*)&smem[wv][0][row][c4] = *(const float4*)src;
      *(float4*)&smem[wv][1][row][c4] = *(const float4*)(src + 1024);
    }
    // (compiler inserts lgkmcnt wait for same-wave LDS RAW dependency)

    float p[KT];
    float tmax = -3.0e38f;
#pragma unroll
    for (int j = 0; j < KT; j++) {
      float sc = 0.f;
#pragma unroll
      for (int d4 = 0; d4 < 16; d4++) {
        float4 kv = *(const float4*)&smem[wv][0][j][d4 * 4];
        sc += q[d4 * 4 + 0] * kv.x + q[d4 * 4 + 1] * kv.y +
              q[d4 * 4 + 2] * kv.z + q[d4 * 4 + 3] * kv.w;
      }
      if (k0 + j > s) sc = -3.0e38f;  // causal mask
      p[j] = sc;
      tmax = fmaxf(tmax, sc);
    }
    float mn    = fmaxf(m, tmax);
    float scale = __expf(m - mn);
    l *= scale;
#pragma unroll
    for (int d = 0; d < HD; d++) o[d] *= scale;
#pragma unroll
    for (int j = 0; j < KT; j++) {
      float pj = __expf(p[j] - mn);
      l += pj;
#pragma unroll
      for (int d4 = 0; d4 < 16; d4++) {
        float4 vv = *(const float4*)&smem[wv][1][j][d4 * 4];
        o[d4 * 4 + 0] += pj * vv.x;
        o[d4 * 4 + 1] += pj * vv.y;
        o[d4 * 4 + 2] += pj * vv.z;
        o[d4 * 4 + 3] += pj * vv.w;
      }
    }
    m = mn;
  }

  // ---- merge the 4 wave-partials per q-row (tiles are dead now) ----
  __syncthreads();
  float* buf = (float*)smem;  // 64 rows x 66 floats = 16.9 KB
  for (int w = 1; w < NSTRIPE; w++) {
    if (wv == w) {
      buf[lane * 66 + 0] = m;
      buf[lane * 66 + 1] = l;
#pragma unroll
      for (int d = 0; d < HD; d++) buf[lane * 66 + 2 + d] = o[d];
    }
    __syncthreads();
    if (wv == 0) {
      float m2 = buf[lane * 66 + 0];
      float l2 = buf[lane * 66 + 1];
      float mn = fmaxf(m, m2);
      float s1 = __expf(m - mn);
      float s2 = __expf(m2 - mn);
      l = l * s1 + l2 * s2;
#pragma unroll
      for (int d = 0; d < HD; d++)
        o[d] = o[d] * s1 + buf[lane * 66 + 2 + d] * s2;
      m = mn;
    }
    __syncthreads();
  }

  if (wv == 0) {
    float inv = 1.f / l;
    float* op = out + (size_t)(b * SEQ + s) * DMODEL + h * HD;
#pragma unroll
    for (int d4 = 0; d4 < 16; d4++) {
      float4 t;
      t.x = o[d4 * 4 + 0] * inv;
      t.y = o[d4 * 4 + 1] * inv;
      t.z = o[d4 * 4 + 2] * inv;
      t.w = o[d4 * 4 + 3] * inv;
      *(float4*)(op + d4 * 4) = t;
    }
  }
}

// ---------------------------------------------------------------------------
// Orchestration
// ---------------------------------------------------------------------------
extern "C" void kernel_launch(void* const* d_in, const int* in_sizes, int n_in,
                              void* d_out, int out_size, void* d_ws, size_t ws_size,
                              hipStream_t stream) {
  const float* x     = (const float*)d_in[0];
  const float* Wq    = (const float*)d_in[1];
  const float* Wk    = (const float*)d_in[2];
  const float* Wv    = (const float*)d_in[3];
  const float* Wp    = (const float*)d_in[4];
  const float* bp    = (const float*)d_in[5];
  const float* W1    = (const float*)d_in[6];
  const float* b1    = (const float*)d_in[7];
  const float* W2    = (const float*)d_in[8];
  const float* b2    = (const float*)d_in[9];
  const float* g1    = (const float*)d_in[10];
  const float* beta1 = (const float*)d_in[11];
  const float* g2    = (const float*)d_in[12];
  const float* beta2 = (const float*)d_in[13];
  float* out = (float*)d_out;

  // Workspace layout (floats). Total 28,311,552 floats = ~108 MB.
  float* wsf = (float*)d_ws;
  float* h   = wsf;                                   // NTOK*DMODEL
  float* Wc  = h + (size_t)NTOK * DMODEL;             // DMODEL*3072
  float* big = Wc + (size_t)DMODEL * 3072;            // NTOK*DFF
  float* x1  = big + (size_t)NTOK * DFF;              // NTOK*DMODEL
  float* qkv = big;
  float* ffn = big;
  float* attno = h;  // reuse: h (LN1 out) is dead after the QKV GEMM

  // 1. LN1
  ln_kernel<<<NTOK, 256, 0, stream>>>(x, g1, beta1, h);
  // 2. pack QKV weights
  repack_qkv<<<(DMODEL * 3072) / 256, 256, 0, stream>>>(Wq, Wk, Wv, Wc);
  // 3. QKV = h @ Wc   (4096 x 3072, K=1024)
  gemm_k<0, 0, 0><<<dim3(3072 / 128, NTOK / 128), 256, 0, stream>>>(
      h, Wc, nullptr, nullptr, qkv, NTOK, 3072, DMODEL);
  // 4. causal attention -> attno (concat-head layout)
  attn_kernel<<<dim3(SEQ / 64, NHEAD, BATCH), 256, 0, stream>>>(qkv, attno);
  // 5. x1 = x + attno @ Wp + bp
  gemm_k<1, 1, 0><<<dim3(DMODEL / 128, NTOK / 128), 256, 0, stream>>>(
      attno, Wp, bp, x, x1, NTOK, DMODEL, DMODEL);
  // 6. LN2 (h buffer free again)
  ln_kernel<<<NTOK, 256, 0, stream>>>(x1, g2, beta2, h);
  // 7. ffn = relu(h @ W1 + b1)   (4096 x 4096, K=1024)
  gemm_k<1, 0, 1><<<dim3(DFF / 128, NTOK / 128), 256, 0, stream>>>(
      h, W1, b1, nullptr, ffn, NTOK, DFF, DMODEL);
  // 8. out = x1 + ffn @ W2 + b2  (4096 x 1024, K=4096)
  gemm_k<1, 1, 0><<<dim3(DMODEL / 128, NTOK / 128), 256, 0, stream>>>(
      ffn, W2, b2, x1, out, NTOK, DMODEL, DFF);
}

// Round 7
// 2562.760 us; speedup vs baseline: 2.0927x; 1.0203x over previous
//
#include <hip/hip_runtime.h>
#include <math.h>

// Problem constants (from reference)
#define DMODEL 1024
#define NHEAD  16
#define HD     64
#define DFF    4096
#define SEQ    2048
#define BATCH  2
#define NTOK   (BATCH * SEQ)   // 4096
#define LN_EPS 1e-5f

typedef __attribute__((ext_vector_type(8))) short short8;
typedef __attribute__((ext_vector_type(4))) float floatx4;
typedef __attribute__((ext_vector_type(4))) unsigned short ushort4v;

// ---- bf16 split helpers: x = hi + lo, both bf16 (RNE) --------------------
__device__ __forceinline__ unsigned short f2bf(float x) {
  unsigned int u = __float_as_uint(x);
  return (unsigned short)((u + 0x7FFFu + ((u >> 16) & 1u)) >> 16);
}
__device__ __forceinline__ float bf2f(unsigned short h) {
  return __uint_as_float(((unsigned int)h) << 16);
}
__device__ __forceinline__ void split2(float x, unsigned short& hi, unsigned short& lo) {
  hi = f2bf(x);
  lo = f2bf(x - bf2f(hi));
}

// ---------------------------------------------------------------------------
// LayerNorm: one block per row (D=1024), 256 threads x float4.
// Writes split-bf16 (hi, lo) outputs for the MFMA GEMMs.
// ---------------------------------------------------------------------------
__global__ __launch_bounds__(256) void ln_split(
    const float* __restrict__ x, const float* __restrict__ g,
    const float* __restrict__ beta, short* __restrict__ ohi,
    short* __restrict__ olo) {
  int row = blockIdx.x;
  const float4* xr = (const float4*)(x + (size_t)row * DMODEL);
  float4 v = xr[threadIdx.x];
  float s  = v.x + v.y + v.z + v.w;
  float sq = v.x * v.x + v.y * v.y + v.z * v.z + v.w * v.w;
#pragma unroll
  for (int off = 1; off < 64; off <<= 1) {
    s  += __shfl_xor(s, off);
    sq += __shfl_xor(sq, off);
  }
  __shared__ float red_s[4], red_q[4];
  int wave = threadIdx.x >> 6, lane = threadIdx.x & 63;
  if (lane == 0) { red_s[wave] = s; red_q[wave] = sq; }
  __syncthreads();
  s  = red_s[0] + red_s[1] + red_s[2] + red_s[3];
  sq = red_q[0] + red_q[1] + red_q[2] + red_q[3];
  float mu  = s * (1.0f / DMODEL);
  float var = sq * (1.0f / DMODEL) - mu * mu;
  float r   = rsqrtf(var + LN_EPS);
  float4 gv = ((const float4*)g)[threadIdx.x];
  float4 bv = ((const float4*)beta)[threadIdx.x];
  float o0 = (v.x - mu) * r * gv.x + bv.x;
  float o1 = (v.y - mu) * r * gv.y + bv.y;
  float o2 = (v.z - mu) * r * gv.z + bv.z;
  float o3 = (v.w - mu) * r * gv.w + bv.w;
  ushort4v hi, lo;
  unsigned short h_, l_;
  split2(o0, h_, l_); hi.x = h_; lo.x = l_;
  split2(o1, h_, l_); hi.y = h_; lo.y = l_;
  split2(o2, h_, l_); hi.z = h_; lo.z = l_;
  split2(o3, h_, l_); hi.w = h_; lo.w = l_;
  size_t base = (size_t)row * DMODEL + threadIdx.x * 4;
  *(ushort4v*)(ohi + base) = hi;
  *(ushort4v*)(olo + base) = lo;
}

// ---------------------------------------------------------------------------
// Build transposed+split QKV weight: WcT[col][d], col = m*1024 + h*64 + k.
// ---------------------------------------------------------------------------
__global__ __launch_bounds__(256) void repack_qkvT(
    const float* __restrict__ Wq, const float* __restrict__ Wk,
    const float* __restrict__ Wv, short* __restrict__ ohi,
    short* __restrict__ olo) {
  int i = blockIdx.x * 256 + threadIdx.x;  // over 3072*1024
  int col = i >> 10;
  int d   = i & 1023;
  int m   = col >> 10;
  int c   = col & 1023;
  const float* W = (m == 0) ? Wq : (m == 1 ? Wk : Wv);
  int hh = c >> 6, kk = c & 63;
  float w = W[((size_t)hh * DMODEL + d) * HD + kk];
  unsigned short h_, l_;
  split2(w, h_, l_);
  ohi[i] = (short)h_;
  olo[i] = (short)l_;
}

// ---------------------------------------------------------------------------
// Generic transpose + split: in[R][C] fp32 -> out[C][R] bf16 hi/lo.
// R must be a power of two (pass lgR). Coalesced 2B writes; reads via L2.
// ---------------------------------------------------------------------------
__global__ __launch_bounds__(256) void transpose_split(
    const float* __restrict__ in, short* __restrict__ ohi,
    short* __restrict__ olo, int lgR, int C) {
  int i = blockIdx.x * 256 + threadIdx.x;  // over C*R
  int R = 1 << lgR;
  int oc = i >> lgR;        // 0..C-1  (output row = original col)
  int orow = i & (R - 1);   // 0..R-1
  float w = in[(size_t)orow * C + oc];
  unsigned short h_, l_;
  split2(w, h_, l_);
  ohi[i] = (short)h_;
  olo[i] = (short)l_;
}

// ---------------------------------------------------------------------------
// Split-bf16 MFMA GEMM: C[M x N] = A[M x K] @ B^T[N x K] with
// A ~ Ahi+Alo, B ~ Bhi+Blo (bf16 pairs). acc += hi*hi + hi*lo + lo*hi
// (3 MFMAs) gives fp32-class precision. Tile 128x128, BK=32, 4 waves at
// 64x64 (4x4 frags of mfma_f32_16x16x32_bf16). LDS [128][40] pad -> 2-way
// bank aliasing (free). Epilogues: 0 = fp32 store; 1 = +bias+res fp32;
// 2 = +bias, ReLU, split-bf16 store.
// ---------------------------------------------------------------------------
template <int MODE>
__global__ __launch_bounds__(256) void gemm_mfma(
    const short* __restrict__ Ahi, const short* __restrict__ Alo,
    const short* __restrict__ Bhi, const short* __restrict__ Blo,
    const float* __restrict__ bias, const float* __restrict__ res,
    float* __restrict__ Cf, short* __restrict__ Chi, short* __restrict__ Clo,
    int M, int N, int K) {
  __shared__ short As[2][128][40];  // [hi/lo][row][k(pad 40)]
  __shared__ short Bs[2][128][40];  // [hi/lo][col][k(pad 40)]
  int tid = threadIdx.x;
  int wv = tid >> 6, lane = tid & 63;
  int wr = (wv >> 1) * 64;  // wave row origin in tile
  int wc = (wv & 1) * 64;   // wave col origin in tile
  int m0 = blockIdx.y * 128, n0 = blockIdx.x * 128;

  int srow = tid >> 1;            // staging row/col 0..127
  int soff = (tid & 1) * 16;      // k sub-offset 0/16
  const short* pAh = Ahi + (size_t)(m0 + srow) * K + soff;
  const short* pAl = Alo + (size_t)(m0 + srow) * K + soff;
  const short* pBh = Bhi + (size_t)(n0 + srow) * K + soff;
  const short* pBl = Blo + (size_t)(n0 + srow) * K + soff;

  int fr = lane & 15;        // row-in-frag (A) / col-in-frag (B)
  int ko = (lane >> 4) * 8;  // k origin for this lane's 8 elements

  floatx4 acc[4][4];
#pragma unroll
  for (int i = 0; i < 4; i++)
#pragma unroll
    for (int j = 0; j < 4; j++) acc[i][j] = (floatx4){0.f, 0.f, 0.f, 0.f};

  for (int k0 = 0; k0 < K; k0 += 32) {
    // global loads into regs (issue before barrier; latency overlaps wait)
    short8 ga0 = *(const short8*)(pAh + k0);
    short8 ga1 = *(const short8*)(pAh + k0 + 8);
    short8 gb0 = *(const short8*)(pAl + k0);
    short8 gb1 = *(const short8*)(pAl + k0 + 8);
    short8 gc0 = *(const short8*)(pBh + k0);
    short8 gc1 = *(const short8*)(pBh + k0 + 8);
    short8 gd0 = *(const short8*)(pBl + k0);
    short8 gd1 = *(const short8*)(pBl + k0 + 8);
    __syncthreads();  // previous iteration's readers done
    *(short8*)&As[0][srow][soff]     = ga0;
    *(short8*)&As[0][srow][soff + 8] = ga1;
    *(short8*)&As[1][srow][soff]     = gb0;
    *(short8*)&As[1][srow][soff + 8] = gb1;
    *(short8*)&Bs[0][srow][soff]     = gc0;
    *(short8*)&Bs[0][srow][soff + 8] = gc1;
    *(short8*)&Bs[1][srow][soff]     = gd0;
    *(short8*)&Bs[1][srow][soff + 8] = gd1;
    __syncthreads();

    short8 ah[4], al[4], bh[4], bl[4];
#pragma unroll
    for (int i = 0; i < 4; i++) {
      ah[i] = *(const short8*)&As[0][wr + i * 16 + fr][ko];
      al[i] = *(const short8*)&As[1][wr + i * 16 + fr][ko];
      bh[i] = *(const short8*)&Bs[0][wc + i * 16 + fr][ko];
      bl[i] = *(const short8*)&Bs[1][wc + i * 16 + fr][ko];
    }
#pragma unroll
    for (int i = 0; i < 4; i++)
#pragma unroll
      for (int j = 0; j < 4; j++) {
        acc[i][j] = __builtin_amdgcn_mfma_f32_16x16x32_bf16(ah[i], bh[j], acc[i][j], 0, 0, 0);
        acc[i][j] = __builtin_amdgcn_mfma_f32_16x16x32_bf16(ah[i], bl[j], acc[i][j], 0, 0, 0);
        acc[i][j] = __builtin_amdgcn_mfma_f32_16x16x32_bf16(al[i], bh[j], acc[i][j], 0, 0, 0);
      }
  }

  // epilogue: C/D layout col = lane&15, row = (lane>>4)*4 + r  [m89-verified]
  int r4 = (lane >> 4) * 4;
#pragma unroll
  for (int i = 0; i < 4; i++)
#pragma unroll
    for (int j = 0; j < 4; j++)
#pragma unroll
      for (int r = 0; r < 4; r++) {
        int row = m0 + wr + i * 16 + r4 + r;
        int col = n0 + wc + j * 16 + fr;
        float v = acc[i][j][r];
        if (MODE == 0) {
          Cf[(size_t)row * N + col] = v;
        } else if (MODE == 1) {
          Cf[(size_t)row * N + col] = v + bias[col] + res[(size_t)row * N + col];
        } else {
          v = fmaxf(v + bias[col], 0.f);
          unsigned short h_, l_;
          split2(v, h_, l_);
          Chi[(size_t)row * N + col] = (short)h_;
          Clo[(size_t)row * N + col] = (short)l_;
        }
      }
}

// ---------------------------------------------------------------------------
// Causal flash attention, fp32 (unchanged round-6 core: 1 q-row/thread,
// 4 key-striped waves, wave-private LDS tiles, no K-loop barrier).
// Epilogue now writes split-bf16 (consumed by the proj MFMA GEMM).
// ---------------------------------------------------------------------------
#define KT 16
#define NSTRIPE 4
__global__ __launch_bounds__(256) void attn_kernel(
    const float* __restrict__ qkv, short* __restrict__ ohi,
    short* __restrict__ olo) {
  int qb = blockIdx.x, h = blockIdx.y, b = blockIdx.z;
  int tid = threadIdx.x;
  int wv = tid >> 6, lane = tid & 63;
  int s = qb * 64 + lane;  // this thread's query row

  __shared__ float smem[NSTRIPE][2][KT][HD];  // per-wave K/V tiles, 32 KB

  float q[HD], o[HD];
  {
    const float4* qp = (const float4*)(qkv + (size_t)(b * SEQ + s) * 3072 + h * HD);
#pragma unroll
    for (int i = 0; i < 16; i++) {
      float4 t = qp[i];
      q[4 * i + 0] = t.x * 0.125f;  // * HD^-0.5
      q[4 * i + 1] = t.y * 0.125f;
      q[4 * i + 2] = t.z * 0.125f;
      q[4 * i + 3] = t.w * 0.125f;
    }
  }
#pragma unroll
  for (int d = 0; d < HD; d++) o[d] = 0.f;
  float m = -1e30f, l = 0.f;

  int ntiles = 4 * qb + 4;  // key tiles covering keys 0 .. qb*64+63
  const float* kbase0 = qkv + (size_t)(b * SEQ) * 3072 + 1024 + h * HD;

  for (int t = wv; t < ntiles; t += NSTRIPE) {
    int k0 = t * KT;
    const float* kbase = kbase0 + (size_t)k0 * 3072;
#pragma unroll
    for (int i = 0; i < 4; i++) {
      int f = lane + 64 * i;  // 0..255 float4 slots
      int row = f >> 4, c4 = (f & 15) * 4;
      const float* src = kbase + (size_t)row * 3072 + c4;
      *(float4*)&smem[wv][0][row][c4] = *(const float4*)src;
      *(float4*)&smem[wv][1][row][c4] = *(const float4*)(src + 1024);
    }

    float p[KT];
    float tmax = -3.0e38f;
#pragma unroll
    for (int j = 0; j < KT; j++) {
      float sc = 0.f;
#pragma unroll
      for (int d4 = 0; d4 < 16; d4++) {
        float4 kv = *(const float4*)&smem[wv][0][j][d4 * 4];
        sc += q[d4 * 4 + 0] * kv.x + q[d4 * 4 + 1] * kv.y +
              q[d4 * 4 + 2] * kv.z + q[d4 * 4 + 3] * kv.w;
      }
      if (k0 + j > s) sc = -3.0e38f;  // causal mask
      p[j] = sc;
      tmax = fmaxf(tmax, sc);
    }
    float mn    = fmaxf(m, tmax);
    float scale = __expf(m - mn);
    l *= scale;
#pragma unroll
    for (int d = 0; d < HD; d++) o[d] *= scale;
#pragma unroll
    for (int j = 0; j < KT; j++) {
      float pj = __expf(p[j] - mn);
      l += pj;
#pragma unroll
      for (int d4 = 0; d4 < 16; d4++) {
        float4 vv = *(const float4*)&smem[wv][1][j][d4 * 4];
        o[d4 * 4 + 0] += pj * vv.x;
        o[d4 * 4 + 1] += pj * vv.y;
        o[d4 * 4 + 2] += pj * vv.z;
        o[d4 * 4 + 3] += pj * vv.w;
      }
    }
    m = mn;
  }

  // ---- merge the 4 wave-partials per q-row (tiles are dead now) ----
  __syncthreads();
  float* buf = (float*)smem;  // 64 rows x 66 floats
  for (int w = 1; w < NSTRIPE; w++) {
    if (wv == w) {
      buf[lane * 66 + 0] = m;
      buf[lane * 66 + 1] = l;
#pragma unroll
      for (int d = 0; d < HD; d++) buf[lane * 66 + 2 + d] = o[d];
    }
    __syncthreads();
    if (wv == 0) {
      float m2 = buf[lane * 66 + 0];
      float l2 = buf[lane * 66 + 1];
      float mn = fmaxf(m, m2);
      float s1 = __expf(m - mn);
      float s2 = __expf(m2 - mn);
      l = l * s1 + l2 * s2;
#pragma unroll
      for (int d = 0; d < HD; d++)
        o[d] = o[d] * s1 + buf[lane * 66 + 2 + d] * s2;
      m = mn;
    }
    __syncthreads();
  }

  if (wv == 0) {
    float inv = 1.f / l;
    size_t base = (size_t)(b * SEQ + s) * DMODEL + h * HD;
#pragma unroll
    for (int d = 0; d < HD; d++) {
      float v = o[d] * inv;
      unsigned short h_, l_;
      split2(v, h_, l_);
      ohi[base + d] = (short)h_;
      olo[base + d] = (short)l_;
    }
  }
}

// ---------------------------------------------------------------------------
// Orchestration
// ---------------------------------------------------------------------------
extern "C" void kernel_launch(void* const* d_in, const int* in_sizes, int n_in,
                              void* d_out, int out_size, void* d_ws, size_t ws_size,
                              hipStream_t stream) {
  const float* x     = (const float*)d_in[0];
  const float* Wq    = (const float*)d_in[1];
  const float* Wk    = (const float*)d_in[2];
  const float* Wv    = (const float*)d_in[3];
  const float* Wp    = (const float*)d_in[4];
  const float* bp    = (const float*)d_in[5];
  const float* W1    = (const float*)d_in[6];
  const float* b1    = (const float*)d_in[7];
  const float* W2    = (const float*)d_in[8];
  const float* b2    = (const float*)d_in[9];
  const float* g1    = (const float*)d_in[10];
  const float* beta1 = (const float*)d_in[11];
  const float* g2    = (const float*)d_in[12];
  const float* beta2 = (const float*)d_in[13];
  float* out = (float*)d_out;

  // Workspace (byte offsets). Peak concurrent usage 100,663,296 B (<113 MB
  // proven in round 3). x1 (post-attn residual) lives in d_out: the FFN2
  // epilogue reads res then writes the same element (same thread) — safe.
  char* ws = (char*)d_ws;
  short* h_hi   = (short*)(ws + 0);           // 8 MiB  (LN1 out)
  short* h_lo   = (short*)(ws + 8388608);     // 8 MiB
  short* WcT_hi = (short*)(ws + 16777216);    // 6 MiB  (QKV weights [3072][1024])
  short* WcT_lo = (short*)(ws + 23068672);    // 6 MiB
  float* qkv    = (float*)(ws + 29360128);    // 48 MiB fp32 (ends 79,691,776)
  short* at_hi  = h_hi;                       // attn out (h dead after QKV GEMM)
  short* at_lo  = h_lo;
  short* WpT_hi = (short*)(ws + 16777216);    // 2 MiB (Wc dead after QKV GEMM)
  short* WpT_lo = (short*)(ws + 18874368);    // 2 MiB
  short* h2_hi  = h_hi;                       // LN2 out (attno dead after proj)
  short* h2_lo  = h_lo;
  short* W1T_hi = (short*)(ws + 16777216);    // 8 MiB [4096][1024]
  short* W1T_lo = (short*)(ws + 25165824);    // 8 MiB (ends 33,554,432)
  short* ffn_hi = (short*)(ws + 33554432);    // 32 MiB [4096][4096]
  short* ffn_lo = (short*)(ws + 67108864);    // 32 MiB (ends 100,663,296)
  short* W2T_hi = (short*)(ws + 0);           // 8 MiB [1024][4096] (h2 dead)
  short* W2T_lo = (short*)(ws + 8388608);     // 8 MiB
  float* x1     = out;                        // residual in d_out

  // 1. LN1 -> split bf16
  ln_split<<<NTOK, 256, 0, stream>>>(x, g1, beta1, h_hi, h_lo);
  // 2. QKV weights: transpose+split -> [3072][1024]
  repack_qkvT<<<(3072 * 1024) / 256, 256, 0, stream>>>(Wq, Wk, Wv, WcT_hi, WcT_lo);
  // 3. qkv = h @ Wc  (fp32 out)
  gemm_mfma<0><<<dim3(3072 / 128, NTOK / 128), 256, 0, stream>>>(
      h_hi, h_lo, WcT_hi, WcT_lo, nullptr, nullptr, qkv, nullptr, nullptr,
      NTOK, 3072, DMODEL);
  // 4. attention -> split bf16 (concat-head layout)
  attn_kernel<<<dim3(SEQ / 64, NHEAD, BATCH), 256, 0, stream>>>(qkv, at_hi, at_lo);
  // 5. Wp: transpose+split -> [1024][1024]
  transpose_split<<<(1024 * 1024) / 256, 256, 0, stream>>>(Wp, WpT_hi, WpT_lo, 10, DMODEL);
  // 6. x1 = x + attno @ Wp + bp  (fp32, into d_out)
  gemm_mfma<1><<<dim3(DMODEL / 128, NTOK / 128), 256, 0, stream>>>(
      at_hi, at_lo, WpT_hi, WpT_lo, bp, x, x1, nullptr, nullptr,
      NTOK, DMODEL, DMODEL);
  // 7. LN2 -> split bf16
  ln_split<<<NTOK, 256, 0, stream>>>(x1, g2, beta2, h2_hi, h2_lo);
  // 8. W1: transpose+split -> [4096][1024]
  transpose_split<<<(1024 * 4096) / 256, 256, 0, stream>>>(W1, W1T_hi, W1T_lo, 10, DFF);
  // 9. ffn = relu(h2 @ W1 + b1) -> split bf16
  gemm_mfma<2><<<dim3(DFF / 128, NTOK / 128), 256, 0, stream>>>(
      h2_hi, h2_lo, W1T_hi, W1T_lo, b1, nullptr, nullptr, ffn_hi, ffn_lo,
      NTOK, DFF, DMODEL);
  // 10. W2: transpose+split -> [1024][4096]
  transpose_split<<<(4096 * 1024) / 256, 256, 0, stream>>>(W2, W2T_hi, W2T_lo, 12, DMODEL);
  // 11. out = x1 + ffn @ W2 + b2  (fp32, res==out aliased per-element)
  gemm_mfma<1><<<dim3(DMODEL / 128, NTOK / 128), 256, 0, stream>>>(
      ffn_hi, ffn_lo, W2T_hi, W2T_lo, b2, x1, out, nullptr, nullptr,
      NTOK, DMODEL, DFF);
}

// Round 11
// 1681.844 us; speedup vs baseline: 3.1888x; 1.5238x over previous
//
#include <hip/hip_runtime.h>
#include <math.h>

// Problem constants (from reference)
#define DMODEL 1024
#define NHEAD  16
#define HD     64
#define DFF    4096
#define SEQ    2048
#define BATCH  2
#define NTOK   (BATCH * SEQ)   // 4096
#define LN_EPS 1e-5f

typedef __attribute__((ext_vector_type(8))) short short8;
typedef __attribute__((ext_vector_type(4))) float floatx4;
typedef __attribute__((ext_vector_type(4))) unsigned short ushort4v;

// ---- bf16 split helpers: x = hi + lo, both bf16 (RNE) --------------------
__device__ __forceinline__ unsigned short f2bf(float x) {
  unsigned int u = __float_as_uint(x);
  return (unsigned short)((u + 0x7FFFu + ((u >> 16) & 1u)) >> 16);
}
__device__ __forceinline__ float bf2f(unsigned short h) {
  return __uint_as_float(((unsigned int)h) << 16);
}
__device__ __forceinline__ void split2(float x, unsigned short& hi, unsigned short& lo) {
  hi = f2bf(x);
  lo = f2bf(x - bf2f(hi));
}

// ---------------------------------------------------------------------------
// LayerNorm: one block per row (D=1024), 256 threads x float4.
// Writes split-bf16 (hi, lo) outputs for the MFMA GEMMs.
// ---------------------------------------------------------------------------
__global__ __launch_bounds__(256) void ln_split(
    const float* __restrict__ x, const float* __restrict__ g,
    const float* __restrict__ beta, short* __restrict__ ohi,
    short* __restrict__ olo) {
  int row = blockIdx.x;
  const float4* xr = (const float4*)(x + (size_t)row * DMODEL);
  float4 v = xr[threadIdx.x];
  float s  = v.x + v.y + v.z + v.w;
  float sq = v.x * v.x + v.y * v.y + v.z * v.z + v.w * v.w;
#pragma unroll
  for (int off = 1; off < 64; off <<= 1) {
    s  += __shfl_xor(s, off);
    sq += __shfl_xor(sq, off);
  }
  __shared__ float red_s[4], red_q[4];
  int wave = threadIdx.x >> 6, lane = threadIdx.x & 63;
  if (lane == 0) { red_s[wave] = s; red_q[wave] = sq; }
  __syncthreads();
  s  = red_s[0] + red_s[1] + red_s[2] + red_s[3];
  sq = red_q[0] + red_q[1] + red_q[2] + red_q[3];
  float mu  = s * (1.0f / DMODEL);
  float var = sq * (1.0f / DMODEL) - mu * mu;
  float r   = rsqrtf(var + LN_EPS);
  float4 gv = ((const float4*)g)[threadIdx.x];
  float4 bv = ((const float4*)beta)[threadIdx.x];
  float o0 = (v.x - mu) * r * gv.x + bv.x;
  float o1 = (v.y - mu) * r * gv.y + bv.y;
  float o2 = (v.z - mu) * r * gv.z + bv.z;
  float o3 = (v.w - mu) * r * gv.w + bv.w;
  ushort4v hi, lo;
  unsigned short h_, l_;
  split2(o0, h_, l_); hi.x = h_; lo.x = l_;
  split2(o1, h_, l_); hi.y = h_; lo.y = l_;
  split2(o2, h_, l_); hi.z = h_; lo.z = l_;
  split2(o3, h_, l_); hi.w = h_; lo.w = l_;
  size_t base = (size_t)row * DMODEL + threadIdx.x * 4;
  *(ushort4v*)(ohi + base) = hi;
  *(ushort4v*)(olo + base) = lo;
}

// ---------------------------------------------------------------------------
// Elementwise split: fp32 -> (hi, lo) bf16. 4 floats/thread.
// ---------------------------------------------------------------------------
__global__ __launch_bounds__(256) void split_rows(
    const float* __restrict__ in, short* __restrict__ ohi,
    short* __restrict__ olo) {
  size_t i = ((size_t)blockIdx.x * 256 + threadIdx.x) * 4;
  float4 v = *(const float4*)(in + i);
  ushort4v hi, lo;
  unsigned short h_, l_;
  split2(v.x, h_, l_); hi.x = h_; lo.x = l_;
  split2(v.y, h_, l_); hi.y = h_; lo.y = l_;
  split2(v.z, h_, l_); hi.z = h_; lo.z = l_;
  split2(v.w, h_, l_); hi.w = h_; lo.w = l_;
  *(ushort4v*)(ohi + i) = hi;
  *(ushort4v*)(olo + i) = lo;
}

// ---------------------------------------------------------------------------
// Build transposed+split QKV weight: WcT[col][d], col = m*1024 + h*64 + k.
// ---------------------------------------------------------------------------
__global__ __launch_bounds__(256) void repack_qkvT(
    const float* __restrict__ Wq, const float* __restrict__ Wk,
    const float* __restrict__ Wv, short* __restrict__ ohi,
    short* __restrict__ olo) {
  int i = blockIdx.x * 256 + threadIdx.x;  // over 3072*1024
  int col = i >> 10;
  int d   = i & 1023;
  int m   = col >> 10;
  int c   = col & 1023;
  const float* W = (m == 0) ? Wq : (m == 1 ? Wk : Wv);
  int hh = c >> 6, kk = c & 63;
  float w = W[((size_t)hh * DMODEL + d) * HD + kk];
  unsigned short h_, l_;
  split2(w, h_, l_);
  ohi[i] = (short)h_;
  olo[i] = (short)l_;
}

// ---------------------------------------------------------------------------
// Generic transpose + split: in[R][C] fp32 -> out[C][R] bf16 hi/lo.
// R must be a power of two (pass lgR). Coalesced 2B writes; reads via L2.
// ---------------------------------------------------------------------------
__global__ __launch_bounds__(256) void transpose_split(
    const float* __restrict__ in, short* __restrict__ ohi,
    short* __restrict__ olo, int lgR, int C) {
  int i = blockIdx.x * 256 + threadIdx.x;  // over C*R
  int R = 1 << lgR;
  int oc = i >> lgR;        // 0..C-1  (output row = original col)
  int orow = i & (R - 1);   // 0..R-1
  float w = in[(size_t)orow * C + oc];
  unsigned short h_, l_;
  split2(w, h_, l_);
  ohi[i] = (short)h_;
  olo[i] = (short)l_;
}

// ---------------------------------------------------------------------------
// Split-bf16 MFMA GEMM: C[M x N] = A[M x K] @ B^T[N x K] with
// A ~ Ahi+Alo, B ~ Bhi+Blo (bf16 pairs). acc += hi*hi + hi*lo + lo*hi
// (3 MFMAs) gives fp32-class precision. Tile 128x128, BK=32, 4 waves at
// 64x64 (4x4 frags of mfma_f32_16x16x32_bf16). LDS [128][40] pad -> 2-way
// bank aliasing (free). Epilogues: 0 = fp32 store; 1 = +bias+res fp32;
// 2 = +bias, ReLU, split-bf16 store.  (Unchanged from measured round 7.)
// ---------------------------------------------------------------------------
template <int MODE>
__global__ __launch_bounds__(256) void gemm_mfma(
    const short* __restrict__ Ahi, const short* __restrict__ Alo,
    const short* __restrict__ Bhi, const short* __restrict__ Blo,
    const float* __restrict__ bias, const float* __restrict__ res,
    float* __restrict__ Cf, short* __restrict__ Chi, short* __restrict__ Clo,
    int M, int N, int K) {
  __shared__ short As[2][128][40];  // [hi/lo][row][k(pad 40)]
  __shared__ short Bs[2][128][40];  // [hi/lo][col][k(pad 40)]
  int tid = threadIdx.x;
  int wv = tid >> 6, lane = tid & 63;
  int wr = (wv >> 1) * 64;  // wave row origin in tile
  int wc = (wv & 1) * 64;   // wave col origin in tile
  int m0 = blockIdx.y * 128, n0 = blockIdx.x * 128;

  int srow = tid >> 1;            // staging row/col 0..127
  int soff = (tid & 1) * 16;      // k sub-offset 0/16
  const short* pAh = Ahi + (size_t)(m0 + srow) * K + soff;
  const short* pAl = Alo + (size_t)(m0 + srow) * K + soff;
  const short* pBh = Bhi + (size_t)(n0 + srow) * K + soff;
  const short* pBl = Blo + (size_t)(n0 + srow) * K + soff;

  int fr = lane & 15;        // row-in-frag (A) / col-in-frag (B)
  int ko = (lane >> 4) * 8;  // k origin for this lane's 8 elements

  floatx4 acc[4][4];
#pragma unroll
  for (int i = 0; i < 4; i++)
#pragma unroll
    for (int j = 0; j < 4; j++) acc[i][j] = (floatx4){0.f, 0.f, 0.f, 0.f};

  for (int k0 = 0; k0 < K; k0 += 32) {
    // global loads into regs (issue before barrier; latency overlaps wait)
    short8 ga0 = *(const short8*)(pAh + k0);
    short8 ga1 = *(const short8*)(pAh + k0 + 8);
    short8 gb0 = *(const short8*)(pAl + k0);
    short8 gb1 = *(const short8*)(pAl + k0 + 8);
    short8 gc0 = *(const short8*)(pBh + k0);
    short8 gc1 = *(const short8*)(pBh + k0 + 8);
    short8 gd0 = *(const short8*)(pBl + k0);
    short8 gd1 = *(const short8*)(pBl + k0 + 8);
    __syncthreads();  // previous iteration's readers done
    *(short8*)&As[0][srow][soff]     = ga0;
    *(short8*)&As[0][srow][soff + 8] = ga1;
    *(short8*)&As[1][srow][soff]     = gb0;
    *(short8*)&As[1][srow][soff + 8] = gb1;
    *(short8*)&Bs[0][srow][soff]     = gc0;
    *(short8*)&Bs[0][srow][soff + 8] = gc1;
    *(short8*)&Bs[1][srow][soff]     = gd0;
    *(short8*)&Bs[1][srow][soff + 8] = gd1;
    __syncthreads();

    short8 ah[4], al[4], bh[4], bl[4];
#pragma unroll
    for (int i = 0; i < 4; i++) {
      ah[i] = *(const short8*)&As[0][wr + i * 16 + fr][ko];
      al[i] = *(const short8*)&As[1][wr + i * 16 + fr][ko];
      bh[i] = *(const short8*)&Bs[0][wc + i * 16 + fr][ko];
      bl[i] = *(const short8*)&Bs[1][wc + i * 16 + fr][ko];
    }
#pragma unroll
    for (int i = 0; i < 4; i++)
#pragma unroll
      for (int j = 0; j < 4; j++) {
        acc[i][j] = __builtin_amdgcn_mfma_f32_16x16x32_bf16(ah[i], bh[j], acc[i][j], 0, 0, 0);
        acc[i][j] = __builtin_amdgcn_mfma_f32_16x16x32_bf16(ah[i], bl[j], acc[i][j], 0, 0, 0);
        acc[i][j] = __builtin_amdgcn_mfma_f32_16x16x32_bf16(al[i], bh[j], acc[i][j], 0, 0, 0);
      }
  }

  // epilogue: C/D layout col = lane&15, row = (lane>>4)*4 + r  [m89-verified]
  int r4 = (lane >> 4) * 4;
#pragma unroll
  for (int i = 0; i < 4; i++)
#pragma unroll
    for (int j = 0; j < 4; j++)
#pragma unroll
      for (int r = 0; r < 4; r++) {
        int row = m0 + wr + i * 16 + r4 + r;
        int col = n0 + wc + j * 16 + fr;
        float v = acc[i][j][r];
        if (MODE == 0) {
          Cf[(size_t)row * N + col] = v;
        } else if (MODE == 1) {
          Cf[(size_t)row * N + col] = v + bias[col] + res[(size_t)row * N + col];
        } else {
          v = fmaxf(v + bias[col], 0.f);
          unsigned short h_, l_;
          split2(v, h_, l_);
          Chi[(size_t)row * N + col] = (short)h_;
          Clo[(size_t)row * N + col] = (short)l_;
        }
      }
}

// ---------------------------------------------------------------------------
// Causal flash attention, fp32 — EXACT round-6 kernel (measured: 1138 µs,
// 128 VGPR, 12% occupancy). fp32 float4 epilogue; the hi/lo split happens
// in split_rows afterwards (round-7's in-kernel split pushed VGPR 128->256
// and halved occupancy: 2018 µs).
// ---------------------------------------------------------------------------
#define KT 16
#define NSTRIPE 4
__global__ __launch_bounds__(256) void attn_kernel(
    const float* __restrict__ qkv, float* __restrict__ out) {
  int qb = blockIdx.x, h = blockIdx.y, b = blockIdx.z;
  int tid = threadIdx.x;
  int wv = tid >> 6, lane = tid & 63;
  int s = qb * 64 + lane;  // this thread's query row

  __shared__ float smem[NSTRIPE][2][KT][HD];  // per-wave K/V tiles, 32 KB

  float q[HD], o[HD];
  {
    const float4* qp = (const float4*)(qkv + (size_t)(b * SEQ + s) * 3072 + h * HD);
#pragma unroll
    for (int i = 0; i < 16; i++) {
      float4 t = qp[i];
      q[4 * i + 0] = t.x * 0.125f;  // * HD^-0.5
      q[4 * i + 1] = t.y * 0.125f;
      q[4 * i + 2] = t.z * 0.125f;
      q[4 * i + 3] = t.w * 0.125f;
    }
  }
#pragma unroll
  for (int d = 0; d < HD; d++) o[d] = 0.f;
  float m = -1e30f, l = 0.f;

  int ntiles = 4 * qb + 4;  // key tiles covering keys 0 .. qb*64+63
  const float* kbase0 = qkv + (size_t)(b * SEQ) * 3072 + 1024 + h * HD;

  for (int t = wv; t < ntiles; t += NSTRIPE) {
    int k0 = t * KT;
    const float* kbase = kbase0 + (size_t)k0 * 3072;
#pragma unroll
    for (int i = 0; i < 4; i++) {
      int f = lane + 64 * i;  // 0..255 float4 slots
      int row = f >> 4, c4 = (f & 15) * 4;
      const float* src = kbase + (size_t)row * 3072 + c4;
      *(float4*)&smem[wv][0][row][c4] = *(const float4*)src;
      *(float4*)&smem[wv][1][row][c4] = *(const float4*)(src + 1024);
    }

    float p[KT];
    float tmax = -3.0e38f;
#pragma unroll
    for (int j = 0; j < KT; j++) {
      float sc = 0.f;
#pragma unroll
      for (int d4 = 0; d4 < 16; d4++) {
        float4 kv = *(const float4*)&smem[wv][0][j][d4 * 4];
        sc += q[d4 * 4 + 0] * kv.x + q[d4 * 4 + 1] * kv.y +
              q[d4 * 4 + 2] * kv.z + q[d4 * 4 + 3] * kv.w;
      }
      if (k0 + j > s) sc = -3.0e38f;  // causal mask
      p[j] = sc;
      tmax = fmaxf(tmax, sc);
    }
    float mn    = fmaxf(m, tmax);
    float scale = __expf(m - mn);
    l *= scale;
#pragma unroll
    for (int d = 0; d < HD; d++) o[d] *= scale;
#pragma unroll
    for (int j = 0; j < KT; j++) {
      float pj = __expf(p[j] - mn);
      l += pj;
#pragma unroll
      for (int d4 = 0; d4 < 16; d4++) {
        float4 vv = *(const float4*)&smem[wv][1][j][d4 * 4];
        o[d4 * 4 + 0] += pj * vv.x;
        o[d4 * 4 + 1] += pj * vv.y;
        o[d4 * 4 + 2] += pj * vv.z;
        o[d4 * 4 + 3] += pj * vv.w;
      }
    }
    m = mn;
  }

  // ---- merge the 4 wave-partials per q-row (tiles are dead now) ----
  __syncthreads();
  float* buf = (float*)smem;  // 64 rows x 66 floats
  for (int w = 1; w < NSTRIPE; w++) {
    if (wv == w) {
      buf[lane * 66 + 0] = m;
      buf[lane * 66 + 1] = l;
#pragma unroll
      for (int d = 0; d < HD; d++) buf[lane * 66 + 2 + d] = o[d];
    }
    __syncthreads();
    if (wv == 0) {
      float m2 = buf[lane * 66 + 0];
      float l2 = buf[lane * 66 + 1];
      float mn = fmaxf(m, m2);
      float s1 = __expf(m - mn);
      float s2 = __expf(m2 - mn);
      l = l * s1 + l2 * s2;
#pragma unroll
      for (int d = 0; d < HD; d++)
        o[d] = o[d] * s1 + buf[lane * 66 + 2 + d] * s2;
      m = mn;
    }
    __syncthreads();
  }

  if (wv == 0) {
    float inv = 1.f / l;
    float* op = out + (size_t)(b * SEQ + s) * DMODEL + h * HD;
#pragma unroll
    for (int d4 = 0; d4 < 16; d4++) {
      float4 t;
      t.x = o[d4 * 4 + 0] * inv;
      t.y = o[d4 * 4 + 1] * inv;
      t.z = o[d4 * 4 + 2] * inv;
      t.w = o[d4 * 4 + 3] * inv;
      *(float4*)(op + d4 * 4) = t;
    }
  }
}

// ---------------------------------------------------------------------------
// Orchestration
// ---------------------------------------------------------------------------
extern "C" void kernel_launch(void* const* d_in, const int* in_sizes, int n_in,
                              void* d_out, int out_size, void* d_ws, size_t ws_size,
                              hipStream_t stream) {
  const float* x     = (const float*)d_in[0];
  const float* Wq    = (const float*)d_in[1];
  const float* Wk    = (const float*)d_in[2];
  const float* Wv    = (const float*)d_in[3];
  const float* Wp    = (const float*)d_in[4];
  const float* bp    = (const float*)d_in[5];
  const float* W1    = (const float*)d_in[6];
  const float* b1    = (const float*)d_in[7];
  const float* W2    = (const float*)d_in[8];
  const float* b2    = (const float*)d_in[9];
  const float* g1    = (const float*)d_in[10];
  const float* beta1 = (const float*)d_in[11];
  const float* g2    = (const float*)d_in[12];
  const float* beta2 = (const float*)d_in[13];
  float* out = (float*)d_out;

  // Workspace layout with liveness (byte offsets; peak 100,663,296 B <
  // 113,246,208 B proven in round 3). x1 lives in d_out (FFN2 epilogue
  // reads res[row][col] then writes the same element in the same thread).
  char* ws = (char*)d_ws;
  short* h_hi     = (short*)(ws + 0);          //  8 MiB, live steps 1-3
  short* h_lo     = (short*)(ws + 8388608);    //  8 MiB
  short* WcT_hi   = (short*)(ws + 16777216);   //  6 MiB, live 2-3
  short* WcT_lo   = (short*)(ws + 23068672);   //  6 MiB
  float* qkv      = (float*)(ws + 29360128);   // 48 MiB fp32, live 3-4 (ends 79,691,776)
  float* attno    = (float*)(ws + 0);          // 16 MiB fp32, live 4-5 (h dead)
  short* at_hi    = (short*)(ws + 16777216);   //  8 MiB, live 5-6 (WcT dead)
  short* at_lo    = (short*)(ws + 25165824);   //  8 MiB (ends 33,554,432; qkv dead)
  short* WpT_hi   = (short*)(ws + 33554432);   //  2 MiB, live 5-6
  short* WpT_lo   = (short*)(ws + 35651584);   //  2 MiB
  short* h2_hi    = (short*)(ws + 0);          //  8 MiB, live 7-9 (attno dead)
  short* h2_lo    = (short*)(ws + 8388608);    //  8 MiB
  short* W1T_hi   = (short*)(ws + 16777216);   //  8 MiB, live 8-9 (at dead)
  short* W1T_lo   = (short*)(ws + 25165824);   //  8 MiB
  short* ffn_hi   = (short*)(ws + 33554432);   // 32 MiB, live 9-11 (WpT dead)
  short* ffn_lo   = (short*)(ws + 67108864);   // 32 MiB (ends 100,663,296)
  short* W2T_hi   = (short*)(ws + 0);          //  8 MiB, live 10-11 (h2 dead)
  short* W2T_lo   = (short*)(ws + 8388608);    //  8 MiB
  float* x1       = out;

  // 1. LN1 -> split bf16
  ln_split<<<NTOK, 256, 0, stream>>>(x, g1, beta1, h_hi, h_lo);
  // 2. QKV weights: transpose+split -> [3072][1024]
  repack_qkvT<<<(3072 * 1024) / 256, 256, 0, stream>>>(Wq, Wk, Wv, WcT_hi, WcT_lo);
  // 3. qkv = h @ Wc  (fp32 out)
  gemm_mfma<0><<<dim3(3072 / 128, NTOK / 128), 256, 0, stream>>>(
      h_hi, h_lo, WcT_hi, WcT_lo, nullptr, nullptr, qkv, nullptr, nullptr,
      NTOK, 3072, DMODEL);
  // 4. attention -> fp32 attno (concat-head layout)
  attn_kernel<<<dim3(SEQ / 64, NHEAD, BATCH), 256, 0, stream>>>(qkv, attno);
  // 4b. split attno -> bf16 hi/lo
  split_rows<<<(NTOK * DMODEL) / 1024, 256, 0, stream>>>(attno, at_hi, at_lo);
  // 5. Wp: transpose+split -> [1024][1024]
  transpose_split<<<(1024 * 1024) / 256, 256, 0, stream>>>(Wp, WpT_hi, WpT_lo, 10, DMODEL);
  // 6. x1 = x + attno @ Wp + bp  (fp32, into d_out)
  gemm_mfma<1><<<dim3(DMODEL / 128, NTOK / 128), 256, 0, stream>>>(
      at_hi, at_lo, WpT_hi, WpT_lo, bp, x, x1, nullptr, nullptr,
      NTOK, DMODEL, DMODEL);
  // 7. LN2 -> split bf16
  ln_split<<<NTOK, 256, 0, stream>>>(x1, g2, beta2, h2_hi, h2_lo);
  // 8. W1: transpose+split -> [4096][1024]
  transpose_split<<<(1024 * 4096) / 256, 256, 0, stream>>>(W1, W1T_hi, W1T_lo, 10, DFF);
  // 9. ffn = relu(h2 @ W1 + b1) -> split bf16
  gemm_mfma<2><<<dim3(DFF / 128, NTOK / 128), 256, 0, stream>>>(
      h2_hi, h2_lo, W1T_hi, W1T_lo, b1, nullptr, nullptr, ffn_hi, ffn_lo,
      NTOK, DFF, DMODEL);
  // 10. W2: transpose+split -> [1024][4096]
  transpose_split<<<(4096 * 1024) / 256, 256, 0, stream>>>(W2, W2T_hi, W2T_lo, 12, DMODEL);
  // 11. out = x1 + ffn @ W2 + b2  (fp32, res==out aliased per-element)
  gemm_mfma<1><<<dim3(DMODEL / 128, NTOK / 128), 256, 0, stream>>>(
      ffn_hi, ffn_lo, W2T_hi, W2T_lo, b2, x1, out, nullptr, nullptr,
      NTOK, DMODEL, DFF);
}

// Round 12
// 1023.141 us; speedup vs baseline: 5.2417x; 1.6438x over previous
//
#include <hip/hip_runtime.h>
#include <math.h>

// Problem constants (from reference)
#define DMODEL 1024
#define NHEAD  16
#define HD     64
#define DFF    4096
#define SEQ    2048
#define BATCH  2
#define NTOK   (BATCH * SEQ)   // 4096
#define LN_EPS 1e-5f

typedef __attribute__((ext_vector_type(8))) short short8;
typedef __attribute__((ext_vector_type(4))) float floatx4;
typedef __attribute__((ext_vector_type(4))) unsigned short ushort4v;

// ---- bf16 split helpers: x = hi + lo, both bf16 (RNE) --------------------
__device__ __forceinline__ unsigned short f2bf(float x) {
  unsigned int u = __float_as_uint(x);
  return (unsigned short)((u + 0x7FFFu + ((u >> 16) & 1u)) >> 16);
}
__device__ __forceinline__ float bf2f(unsigned short h) {
  return __uint_as_float(((unsigned int)h) << 16);
}
__device__ __forceinline__ void split2(float x, unsigned short& hi, unsigned short& lo) {
  hi = f2bf(x);
  lo = f2bf(x - bf2f(hi));
}

// ---------------------------------------------------------------------------
// LayerNorm: one block per row (D=1024), 256 threads x float4.
// Writes split-bf16 (hi, lo) outputs for the MFMA GEMMs.
// ---------------------------------------------------------------------------
__global__ __launch_bounds__(256) void ln_split(
    const float* __restrict__ x, const float* __restrict__ g,
    const float* __restrict__ beta, short* __restrict__ ohi,
    short* __restrict__ olo) {
  int row = blockIdx.x;
  const float4* xr = (const float4*)(x + (size_t)row * DMODEL);
  float4 v = xr[threadIdx.x];
  float s  = v.x + v.y + v.z + v.w;
  float sq = v.x * v.x + v.y * v.y + v.z * v.z + v.w * v.w;
#pragma unroll
  for (int off = 1; off < 64; off <<= 1) {
    s  += __shfl_xor(s, off);
    sq += __shfl_xor(sq, off);
  }
  __shared__ float red_s[4], red_q[4];
  int wave = threadIdx.x >> 6, lane = threadIdx.x & 63;
  if (lane == 0) { red_s[wave] = s; red_q[wave] = sq; }
  __syncthreads();
  s  = red_s[0] + red_s[1] + red_s[2] + red_s[3];
  sq = red_q[0] + red_q[1] + red_q[2] + red_q[3];
  float mu  = s * (1.0f / DMODEL);
  float var = sq * (1.0f / DMODEL) - mu * mu;
  float r   = rsqrtf(var + LN_EPS);
  float4 gv = ((const float4*)g)[threadIdx.x];
  float4 bv = ((const float4*)beta)[threadIdx.x];
  float o0 = (v.x - mu) * r * gv.x + bv.x;
  float o1 = (v.y - mu) * r * gv.y + bv.y;
  float o2 = (v.z - mu) * r * gv.z + bv.z;
  float o3 = (v.w - mu) * r * gv.w + bv.w;
  ushort4v hi, lo;
  unsigned short h_, l_;
  split2(o0, h_, l_); hi.x = h_; lo.x = l_;
  split2(o1, h_, l_); hi.y = h_; lo.y = l_;
  split2(o2, h_, l_); hi.z = h_; lo.z = l_;
  split2(o3, h_, l_); hi.w = h_; lo.w = l_;
  size_t base = (size_t)row * DMODEL + threadIdx.x * 4;
  *(ushort4v*)(ohi + base) = hi;
  *(ushort4v*)(olo + base) = lo;
}

// ---------------------------------------------------------------------------
// Elementwise split: fp32 -> (hi, lo) bf16. 4 floats/thread.
// ---------------------------------------------------------------------------
__global__ __launch_bounds__(256) void split_rows(
    const float* __restrict__ in, short* __restrict__ ohi,
    short* __restrict__ olo) {
  size_t i = ((size_t)blockIdx.x * 256 + threadIdx.x) * 4;
  float4 v = *(const float4*)(in + i);
  ushort4v hi, lo;
  unsigned short h_, l_;
  split2(v.x, h_, l_); hi.x = h_; lo.x = l_;
  split2(v.y, h_, l_); hi.y = h_; lo.y = l_;
  split2(v.z, h_, l_); hi.z = h_; lo.z = l_;
  split2(v.w, h_, l_); hi.w = h_; lo.w = l_;
  *(ushort4v*)(ohi + i) = hi;
  *(ushort4v*)(olo + i) = lo;
}

// ---------------------------------------------------------------------------
// Build transposed+split QKV weight: WcT[col][d], col = m*1024 + h*64 + k.
// ---------------------------------------------------------------------------
__global__ __launch_bounds__(256) void repack_qkvT(
    const float* __restrict__ Wq, const float* __restrict__ Wk,
    const float* __restrict__ Wv, short* __restrict__ ohi,
    short* __restrict__ olo) {
  int i = blockIdx.x * 256 + threadIdx.x;  // over 3072*1024
  int col = i >> 10;
  int d   = i & 1023;
  int m   = col >> 10;
  int c   = col & 1023;
  const float* W = (m == 0) ? Wq : (m == 1 ? Wk : Wv);
  int hh = c >> 6, kk = c & 63;
  float w = W[((size_t)hh * DMODEL + d) * HD + kk];
  unsigned short h_, l_;
  split2(w, h_, l_);
  ohi[i] = (short)h_;
  olo[i] = (short)l_;
}

// ---------------------------------------------------------------------------
// Generic transpose + split: in[R][C] fp32 -> out[C][R] bf16 hi/lo.
// ---------------------------------------------------------------------------
__global__ __launch_bounds__(256) void transpose_split(
    const float* __restrict__ in, short* __restrict__ ohi,
    short* __restrict__ olo, int lgR, int C) {
  int i = blockIdx.x * 256 + threadIdx.x;  // over C*R
  int R = 1 << lgR;
  int oc = i >> lgR;        // 0..C-1  (output row = original col)
  int orow = i & (R - 1);   // 0..R-1
  float w = in[(size_t)orow * C + oc];
  unsigned short h_, l_;
  split2(w, h_, l_);
  ohi[i] = (short)h_;
  olo[i] = (short)l_;
}

// ---------------------------------------------------------------------------
// Split-bf16 MFMA GEMM (unchanged from measured round 7/11).
// ---------------------------------------------------------------------------
template <int MODE>
__global__ __launch_bounds__(256) void gemm_mfma(
    const short* __restrict__ Ahi, const short* __restrict__ Alo,
    const short* __restrict__ Bhi, const short* __restrict__ Blo,
    const float* __restrict__ bias, const float* __restrict__ res,
    float* __restrict__ Cf, short* __restrict__ Chi, short* __restrict__ Clo,
    int M, int N, int K) {
  __shared__ short As[2][128][40];  // [hi/lo][row][k(pad 40)]
  __shared__ short Bs[2][128][40];  // [hi/lo][col][k(pad 40)]
  int tid = threadIdx.x;
  int wv = tid >> 6, lane = tid & 63;
  int wr = (wv >> 1) * 64;
  int wc = (wv & 1) * 64;
  int m0 = blockIdx.y * 128, n0 = blockIdx.x * 128;

  int srow = tid >> 1;
  int soff = (tid & 1) * 16;
  const short* pAh = Ahi + (size_t)(m0 + srow) * K + soff;
  const short* pAl = Alo + (size_t)(m0 + srow) * K + soff;
  const short* pBh = Bhi + (size_t)(n0 + srow) * K + soff;
  const short* pBl = Blo + (size_t)(n0 + srow) * K + soff;

  int fr = lane & 15;
  int ko = (lane >> 4) * 8;

  floatx4 acc[4][4];
#pragma unroll
  for (int i = 0; i < 4; i++)
#pragma unroll
    for (int j = 0; j < 4; j++) acc[i][j] = (floatx4){0.f, 0.f, 0.f, 0.f};

  for (int k0 = 0; k0 < K; k0 += 32) {
    short8 ga0 = *(const short8*)(pAh + k0);
    short8 ga1 = *(const short8*)(pAh + k0 + 8);
    short8 gb0 = *(const short8*)(pAl + k0);
    short8 gb1 = *(const short8*)(pAl + k0 + 8);
    short8 gc0 = *(const short8*)(pBh + k0);
    short8 gc1 = *(const short8*)(pBh + k0 + 8);
    short8 gd0 = *(const short8*)(pBl + k0);
    short8 gd1 = *(const short8*)(pBl + k0 + 8);
    __syncthreads();
    *(short8*)&As[0][srow][soff]     = ga0;
    *(short8*)&As[0][srow][soff + 8] = ga1;
    *(short8*)&As[1][srow][soff]     = gb0;
    *(short8*)&As[1][srow][soff + 8] = gb1;
    *(short8*)&Bs[0][srow][soff]     = gc0;
    *(short8*)&Bs[0][srow][soff + 8] = gc1;
    *(short8*)&Bs[1][srow][soff]     = gd0;
    *(short8*)&Bs[1][srow][soff + 8] = gd1;
    __syncthreads();

    short8 ah[4], al[4], bh[4], bl[4];
#pragma unroll
    for (int i = 0; i < 4; i++) {
      ah[i] = *(const short8*)&As[0][wr + i * 16 + fr][ko];
      al[i] = *(const short8*)&As[1][wr + i * 16 + fr][ko];
      bh[i] = *(const short8*)&Bs[0][wc + i * 16 + fr][ko];
      bl[i] = *(const short8*)&Bs[1][wc + i * 16 + fr][ko];
    }
#pragma unroll
    for (int i = 0; i < 4; i++)
#pragma unroll
      for (int j = 0; j < 4; j++) {
        acc[i][j] = __builtin_amdgcn_mfma_f32_16x16x32_bf16(ah[i], bh[j], acc[i][j], 0, 0, 0);
        acc[i][j] = __builtin_amdgcn_mfma_f32_16x16x32_bf16(ah[i], bl[j], acc[i][j], 0, 0, 0);
        acc[i][j] = __builtin_amdgcn_mfma_f32_16x16x32_bf16(al[i], bh[j], acc[i][j], 0, 0, 0);
      }
  }

  int r4 = (lane >> 4) * 4;
#pragma unroll
  for (int i = 0; i < 4; i++)
#pragma unroll
    for (int j = 0; j < 4; j++)
#pragma unroll
      for (int r = 0; r < 4; r++) {
        int row = m0 + wr + i * 16 + r4 + r;
        int col = n0 + wc + j * 16 + fr;
        float v = acc[i][j][r];
        if (MODE == 0) {
          Cf[(size_t)row * N + col] = v;
        } else if (MODE == 1) {
          Cf[(size_t)row * N + col] = v + bias[col] + res[(size_t)row * N + col];
        } else {
          v = fmaxf(v + bias[col], 0.f);
          unsigned short h_, l_;
          split2(v, h_, l_);
          Chi[(size_t)row * N + col] = (short)h_;
          Clo[(size_t)row * N + col] = (short)l_;
        }
      }
}

// ---------------------------------------------------------------------------
// MFMA causal flash attention, split-bf16 (fp32-class numerics).
// Block = (64 q-rows, head, batch), 4 waves; wave wv owns q-frag rows
// q0 = qb*64 + wv*16 (+ l&15). NO __syncthreads: K/V frags are loaded
// directly global->registers (L2-resident per head), P redistribution goes
// through WAVE-PRIVATE LDS (same-wave lgkmcnt ordering, compiler-inserted).
// Fragment layouts identical to the measured-passing gemm_mfma:
//   A-frag row=l&15, k=(l>>4)*8 ; B-frag col=l&15, k=(l>>4)*8 ;
//   C/D row=(l>>4)*4+r, col=l&15  [m89-verified].
// QK^T: D[q][key] = Q-frag x K-frag (contraction d, 2 chunks of 32).
// PV:   D[q][d]   = P-frag x V-frag (contraction key, 32 per tile).
// All operands split hi+lo, 3 MFMAs per product -> fp32-class precision.
// ---------------------------------------------------------------------------
#define KT2 32
__global__ __launch_bounds__(256) void attn_mfma(
    const float* __restrict__ qkv, float* __restrict__ out) {
  int qb = blockIdx.x, h = blockIdx.y, b = blockIdx.z;
  int tid = threadIdx.x;
  int wv = tid >> 6, lane = tid & 63;
  int lr = lane & 15;   // frag row (A) / col (B/D)
  int lg = lane >> 4;   // 0..3: k-group (frags), row-group (C/D)

  __shared__ short P_hi[4][16][40];  // wave-private P tiles (pad 40)
  __shared__ short P_lo[4][16][40];

  int q0 = qb * 64 + wv * 16;

  // ---- Q A-frags (2 d-chunks), pre-scaled by HD^-0.5, split hi/lo ----
  short8 qh[2], ql[2];
  {
    const float* qp = qkv + (size_t)(b * SEQ + q0 + lr) * 3072 + h * HD + lg * 8;
#pragma unroll
    for (int dc = 0; dc < 2; dc++) {
      float4 a = *(const float4*)(qp + dc * 32);
      float4 c = *(const float4*)(qp + dc * 32 + 4);
      float vals[8] = {a.x, a.y, a.z, a.w, c.x, c.y, c.z, c.w};
#pragma unroll
      for (int j = 0; j < 8; j++) {
        unsigned short h_, l_;
        split2(vals[j] * 0.125f, h_, l_);
        qh[dc][j] = (short)h_;
        ql[dc][j] = (short)l_;
      }
    }
  }

  floatx4 o_acc[4];
#pragma unroll
  for (int df = 0; df < 4; df++) o_acc[df] = (floatx4){0.f, 0.f, 0.f, 0.f};
  float m_st[4] = {-1e30f, -1e30f, -1e30f, -1e30f};
  float l_st[4] = {0.f, 0.f, 0.f, 0.f};

  const float* kbase = qkv + (size_t)(b * SEQ) * 3072 + 1024 + h * HD;
  const float* vbase = qkv + (size_t)(b * SEQ) * 3072 + 2048 + h * HD;

  int ntiles = (q0 + 15) / KT2 + 1;  // per-wave: covers keys <= wave's max q

  for (int t = 0; t < ntiles; t++) {
    int k0 = t * KT2;

    // ---- K B-frags direct from global (row k0+kf*16+lr, 8 d each) ----
    short8 kh[2][2], kl[2][2];
#pragma unroll
    for (int kf = 0; kf < 2; kf++) {
      const float* kp = kbase + (size_t)(k0 + kf * 16 + lr) * 3072 + lg * 8;
#pragma unroll
      for (int dc = 0; dc < 2; dc++) {
        float4 a = *(const float4*)(kp + dc * 32);
        float4 c = *(const float4*)(kp + dc * 32 + 4);
        float vals[8] = {a.x, a.y, a.z, a.w, c.x, c.y, c.z, c.w};
#pragma unroll
        for (int j = 0; j < 8; j++) {
          unsigned short h_, l_;
          split2(vals[j], h_, l_);
          kh[kf][dc][j] = (short)h_;
          kl[kf][dc][j] = (short)l_;
        }
      }
    }

    // ---- QK^T: s[kf] (C/D layout: row=q=lg*4+r, col=key=kf*16+lr) ----
    floatx4 s[2];
#pragma unroll
    for (int kf = 0; kf < 2; kf++) {
      floatx4 acc = (floatx4){0.f, 0.f, 0.f, 0.f};
#pragma unroll
      for (int dc = 0; dc < 2; dc++) {
        acc = __builtin_amdgcn_mfma_f32_16x16x32_bf16(qh[dc], kh[kf][dc], acc, 0, 0, 0);
        acc = __builtin_amdgcn_mfma_f32_16x16x32_bf16(qh[dc], kl[kf][dc], acc, 0, 0, 0);
        acc = __builtin_amdgcn_mfma_f32_16x16x32_bf16(ql[dc], kh[kf][dc], acc, 0, 0, 0);
      }
      s[kf] = acc;
    }

    // ---- causal mask + row-max (reduce over 16-lane col group) ----
    float tmax[4];
#pragma unroll
    for (int r = 0; r < 4; r++) {
      int qg = q0 + lg * 4 + r;
#pragma unroll
      for (int kf = 0; kf < 2; kf++)
        if (k0 + kf * 16 + lr > qg) s[kf][r] = -3.0e38f;
      tmax[r] = fmaxf(s[0][r], s[1][r]);
    }
#pragma unroll
    for (int off = 1; off < 16; off <<= 1)
#pragma unroll
      for (int r = 0; r < 4; r++)
        tmax[r] = fmaxf(tmax[r], __shfl_xor(tmax[r], off));

    // ---- online softmax update (per-lane partial l; reduce at end) ----
    float p0[4], p1[4];
#pragma unroll
    for (int r = 0; r < 4; r++) {
      float mn = fmaxf(m_st[r], tmax[r]);
      float sc = __expf(m_st[r] - mn);
      m_st[r] = mn;
      p0[r] = __expf(s[0][r] - mn);
      p1[r] = __expf(s[1][r] - mn);
      l_st[r] = l_st[r] * sc + p0[r] + p1[r];
#pragma unroll
      for (int df = 0; df < 4; df++) o_acc[df][r] *= sc;
    }

    // ---- P (C/D layout) -> wave-private LDS as split bf16 ----
#pragma unroll
    for (int r = 0; r < 4; r++) {
      unsigned short h_, l_;
      split2(p0[r], h_, l_);
      P_hi[wv][lg * 4 + r][lr] = (short)h_;
      P_lo[wv][lg * 4 + r][lr] = (short)l_;
      split2(p1[r], h_, l_);
      P_hi[wv][lg * 4 + r][16 + lr] = (short)h_;
      P_lo[wv][lg * 4 + r][16 + lr] = (short)l_;
    }
    // ---- read P back as A-frag (same-wave RAW: compiler lgkmcnt) ----
    short8 ph = *(const short8*)&P_hi[wv][lr][lg * 8];
    short8 pl = *(const short8*)&P_lo[wv][lr][lg * 8];

    // ---- V B-frags direct from global (transposed access) + PV ----
#pragma unroll
    for (int df = 0; df < 4; df++) {
      const float* vp = vbase + (size_t)(k0 + lg * 8) * 3072 + df * 16 + lr;
      float vals[8];
#pragma unroll
      for (int j = 0; j < 8; j++) vals[j] = vp[(size_t)j * 3072];
      short8 vh, vl;
#pragma unroll
      for (int j = 0; j < 8; j++) {
        unsigned short h_, l_;
        split2(vals[j], h_, l_);
        vh[j] = (short)h_;
        vl[j] = (short)l_;
      }
      o_acc[df] = __builtin_amdgcn_mfma_f32_16x16x32_bf16(ph, vh, o_acc[df], 0, 0, 0);
      o_acc[df] = __builtin_amdgcn_mfma_f32_16x16x32_bf16(ph, vl, o_acc[df], 0, 0, 0);
      o_acc[df] = __builtin_amdgcn_mfma_f32_16x16x32_bf16(pl, vh, o_acc[df], 0, 0, 0);
    }
  }

  // ---- final l row-sum across the 16-lane col group ----
#pragma unroll
  for (int off = 1; off < 16; off <<= 1)
#pragma unroll
    for (int r = 0; r < 4; r++)
      l_st[r] += __shfl_xor(l_st[r], off);

  // ---- write O (C/D layout -> concat-head fp32) ----
#pragma unroll
  for (int r = 0; r < 4; r++) {
    float inv = 1.f / l_st[r];
    float* op = out + (size_t)(b * SEQ + q0 + lg * 4 + r) * DMODEL + h * HD;
#pragma unroll
    for (int df = 0; df < 4; df++)
      op[df * 16 + lr] = o_acc[df][r] * inv;
  }
}

// ---------------------------------------------------------------------------
// Orchestration
// ---------------------------------------------------------------------------
extern "C" void kernel_launch(void* const* d_in, const int* in_sizes, int n_in,
                              void* d_out, int out_size, void* d_ws, size_t ws_size,
                              hipStream_t stream) {
  const float* x     = (const float*)d_in[0];
  const float* Wq    = (const float*)d_in[1];
  const float* Wk    = (const float*)d_in[2];
  const float* Wv    = (const float*)d_in[3];
  const float* Wp    = (const float*)d_in[4];
  const float* bp    = (const float*)d_in[5];
  const float* W1    = (const float*)d_in[6];
  const float* b1    = (const float*)d_in[7];
  const float* W2    = (const float*)d_in[8];
  const float* b2    = (const float*)d_in[9];
  const float* g1    = (const float*)d_in[10];
  const float* beta1 = (const float*)d_in[11];
  const float* g2    = (const float*)d_in[12];
  const float* beta2 = (const float*)d_in[13];
  float* out = (float*)d_out;

  // Workspace layout with liveness (peak 100,663,296 B). x1 lives in d_out.
  char* ws = (char*)d_ws;
  short* h_hi     = (short*)(ws + 0);          //  8 MiB, live steps 1-3
  short* h_lo     = (short*)(ws + 8388608);    //  8 MiB
  short* WcT_hi   = (short*)(ws + 16777216);   //  6 MiB, live 2-3
  short* WcT_lo   = (short*)(ws + 23068672);   //  6 MiB
  float* qkv      = (float*)(ws + 29360128);   // 48 MiB fp32, live 3-4
  float* attno    = (float*)(ws + 0);          // 16 MiB fp32, live 4-5
  short* at_hi    = (short*)(ws + 16777216);   //  8 MiB, live 5-6
  short* at_lo    = (short*)(ws + 25165824);   //  8 MiB
  short* WpT_hi   = (short*)(ws + 33554432);   //  2 MiB, live 5-6
  short* WpT_lo   = (short*)(ws + 35651584);   //  2 MiB
  short* h2_hi    = (short*)(ws + 0);          //  8 MiB, live 7-9
  short* h2_lo    = (short*)(ws + 8388608);    //  8 MiB
  short* W1T_hi   = (short*)(ws + 16777216);   //  8 MiB, live 8-9
  short* W1T_lo   = (short*)(ws + 25165824);   //  8 MiB
  short* ffn_hi   = (short*)(ws + 33554432);   // 32 MiB, live 9-11
  short* ffn_lo   = (short*)(ws + 67108864);   // 32 MiB
  short* W2T_hi   = (short*)(ws + 0);          //  8 MiB, live 10-11
  short* W2T_lo   = (short*)(ws + 8388608);    //  8 MiB
  float* x1       = out;

  // 1. LN1 -> split bf16
  ln_split<<<NTOK, 256, 0, stream>>>(x, g1, beta1, h_hi, h_lo);
  // 2. QKV weights: transpose+split -> [3072][1024]
  repack_qkvT<<<(3072 * 1024) / 256, 256, 0, stream>>>(Wq, Wk, Wv, WcT_hi, WcT_lo);
  // 3. qkv = h @ Wc  (fp32 out)
  gemm_mfma<0><<<dim3(3072 / 128, NTOK / 128), 256, 0, stream>>>(
      h_hi, h_lo, WcT_hi, WcT_lo, nullptr, nullptr, qkv, nullptr, nullptr,
      NTOK, 3072, DMODEL);
  // 4. MFMA attention -> fp32 attno (concat-head layout)
  attn_mfma<<<dim3(SEQ / 64, NHEAD, BATCH), 256, 0, stream>>>(qkv, attno);
  // 4b. split attno -> bf16 hi/lo
  split_rows<<<(NTOK * DMODEL) / 1024, 256, 0, stream>>>(attno, at_hi, at_lo);
  // 5. Wp: transpose+split -> [1024][1024]
  transpose_split<<<(1024 * 1024) / 256, 256, 0, stream>>>(Wp, WpT_hi, WpT_lo, 10, DMODEL);
  // 6. x1 = x + attno @ Wp + bp  (fp32, into d_out)
  gemm_mfma<1><<<dim3(DMODEL / 128, NTOK / 128), 256, 0, stream>>>(
      at_hi, at_lo, WpT_hi, WpT_lo, bp, x, x1, nullptr, nullptr,
      NTOK, DMODEL, DMODEL);
  // 7. LN2 -> split bf16
  ln_split<<<NTOK, 256, 0, stream>>>(x1, g2, beta2, h2_hi, h2_lo);
  // 8. W1: transpose+split -> [4096][1024]
  transpose_split<<<(1024 * 4096) / 256, 256, 0, stream>>>(W1, W1T_hi, W1T_lo, 10, DFF);
  // 9. ffn = relu(h2 @ W1 + b1) -> split bf16
  gemm_mfma<2><<<dim3(DFF / 128, NTOK / 128), 256, 0, stream>>>(
      h2_hi, h2_lo, W1T_hi, W1T_lo, b1, nullptr, nullptr, ffn_hi, ffn_lo,
      NTOK, DFF, DMODEL);
  // 10. W2: transpose+split -> [1024][4096]
  transpose_split<<<(4096 * 1024) / 256, 256, 0, stream>>>(W2, W2T_hi, W2T_lo, 12, DMODEL);
  // 11. out = x1 + ffn @ W2 + b2  (fp32, res==out aliased per-element)
  gemm_mfma<1><<<dim3(DMODEL / 128, NTOK / 128), 256, 0, stream>>>(
      ffn_hi, ffn_lo, W2T_hi, W2T_lo, b2, x1, out, nullptr, nullptr,
      NTOK, DMODEL, DFF);
}